// Round 1
// baseline (1040.948 us; speedup 1.0000x reference)
//
#include <hip/hip_runtime.h>
#include <math.h>

// FNet mixing: out = Re(FFT2(x, axes=(1,2))), x: [B=4, S=8192, D=768] f32.
// Separable: Stage A = FFT along D (768 = 3 x 256 mixed radix), complex out
// (re -> d_out, im -> d_ws). Stage B = FFT along S (8192, radix-2), real part
// only -> d_out.

#define BATCH 4
#define S_LEN 8192
#define D_LEN 768

__device__ __forceinline__ void cmul(float ar, float ai, float br, float bi,
                                     float& cr, float& ci) {
    cr = ar * br - ai * bi;
    ci = ar * bi + ai * br;
}

// ---------------- Stage A: FFT-768 per row ----------------
// 768 = N1*N2 with N1=256, N2=3. Input n = 3*n1 + n2; output k = k1 + 256*k2.
// U_{n2} = FFT_256(x[3*n1+n2]); X[k1+256*k2] = sum_{n2} U_{n2}[k1] *
//   W768^{n2*k1} * W3^{n2*k2}.
__global__ __launch_bounds__(128) void fft_d_kernel(const float* __restrict__ x,
                                                    float* __restrict__ out_re,
                                                    float* __restrict__ out_im) {
    __shared__ float sre[768];
    __shared__ float sim[768];
    const int row = blockIdx.x;           // 0 .. B*S-1
    const int t = threadIdx.x;
    const float* xr = x + (size_t)row * D_LEN;

    // Coalesced load, scatter to lds[(n%3)*256 + n/3]; imag = 0.
    for (int n = t; n < D_LEN; n += 128) {
        int n1 = n / 3;
        int n2 = n - 3 * n1;
        sre[n2 * 256 + n1] = xr[n];
        sim[n2 * 256 + n1] = 0.0f;
    }
    __syncthreads();

    // Three in-place DIF FFT-256 (output bit-reversed within each subarray).
    for (int sh = 7; sh >= 0; --sh) {
        const int half = 1 << sh;
        const int len = half << 1;
        const float wstep = -6.28318530717958647692f / (float)len;
        for (int sub = 0; sub < 3; ++sub) {
            const int i = t;              // 128 butterflies per subarray
            const int g = i >> sh;
            const int p = i & (half - 1);
            const int i0 = sub * 256 + (g << (sh + 1)) + p;
            const int i1 = i0 + half;
            float ar = sre[i0], ai = sim[i0];
            float br = sre[i1], bi = sim[i1];
            sre[i0] = ar + br;
            sim[i0] = ai + bi;
            float dr = ar - br, di = ai - bi;
            float s, c;
            sincosf(wstep * (float)p, &s, &c);
            sre[i1] = dr * c - di * s;
            sim[i1] = dr * s + di * c;
        }
        __syncthreads();
    }

    // Radix-3 combine + write (coalesced 512B runs).
    const float W3r = -0.5f;
    const float W3i = -0.86602540378443864676f;  // sin(-2pi/3)
    const size_t obase = (size_t)row * D_LEN;
    for (int k1 = t; k1 < 256; k1 += 128) {
        const int j = (int)(__brev((unsigned)k1) >> 24);  // br8
        float u0r = sre[j], u0i = sim[j];
        float u1r = sre[256 + j], u1i = sim[256 + j];
        float u2r = sre[512 + j], u2i = sim[512 + j];
        float ang = -6.28318530717958647692f * (float)k1 * (1.0f / 768.0f);
        float s1, c1, s2, c2;
        sincosf(ang, &s1, &c1);
        sincosf(2.0f * ang, &s2, &c2);
        float v1r, v1i, v2r, v2i;
        cmul(u1r, u1i, c1, s1, v1r, v1i);
        cmul(u2r, u2i, c2, s2, v2r, v2i);
        // k2 = 0
        out_re[obase + k1] = u0r + v1r + v2r;
        out_im[obase + k1] = u0i + v1i + v2i;
        // k2 = 1: u0 + v1*W3 + v2*W3^2   (W3^2 = conj(W3))
        float a1r, a1i, a2r, a2i;
        cmul(v1r, v1i, W3r, W3i, a1r, a1i);
        cmul(v2r, v2i, W3r, -W3i, a2r, a2i);
        out_re[obase + 256 + k1] = u0r + a1r + a2r;
        out_im[obase + 256 + k1] = u0i + a1i + a2i;
        // k2 = 2: u0 + v1*W3^2 + v2*W3
        cmul(v1r, v1i, W3r, -W3i, a1r, a1i);
        cmul(v2r, v2i, W3r, W3i, a2r, a2i);
        out_re[obase + 512 + k1] = u0r + a1r + a2r;
        out_im[obase + 512 + k1] = u0i + a1i + a2i;
    }
}

// ---------------- Stage B: FFT-8192 per column, real part out ----------------
__global__ __launch_bounds__(256) void fft_s_kernel(const float* __restrict__ in_re,
                                                    const float* __restrict__ in_im,
                                                    float* __restrict__ out) {
    __shared__ float sre[S_LEN];
    __shared__ float sim[S_LEN];
    const int col = blockIdx.x;           // 0 .. B*D-1
    const int b = col / D_LEN;
    const int d = col - b * D_LEN;
    const int t = threadIdx.x;
    const size_t base = (size_t)b * S_LEN * D_LEN + d;

    for (int j = t; j < S_LEN; j += 256) {
        sre[j] = in_re[base + (size_t)j * D_LEN];
        sim[j] = in_im[base + (size_t)j * D_LEN];
    }
    __syncthreads();

    for (int sh = 12; sh >= 0; --sh) {
        const int half = 1 << sh;
        const int len = half << 1;
        const float wstep = -6.28318530717958647692f / (float)len;
        for (int i = t; i < (S_LEN / 2); i += 256) {
            const int g = i >> sh;
            const int p = i & (half - 1);
            const int i0 = (g << (sh + 1)) + p;
            const int i1 = i0 + half;
            float ar = sre[i0], ai = sim[i0];
            float br = sre[i1], bi = sim[i1];
            sre[i0] = ar + br;
            sim[i0] = ai + bi;
            float dr = ar - br, di = ai - bi;
            float s, c;
            sincosf(wstep * (float)p, &s, &c);
            sre[i1] = dr * c - di * s;
            sim[i1] = dr * s + di * c;
        }
        __syncthreads();
    }

    // Real part only, un-bit-reverse on the way out.
    for (int j = t; j < S_LEN; j += 256) {
        const int k = (int)(__brev((unsigned)j) >> 19);  // br13
        out[base + (size_t)k * D_LEN] = sre[j];
    }
}

extern "C" void kernel_launch(void* const* d_in, const int* in_sizes, int n_in,
                              void* d_out, int out_size, void* d_ws, size_t ws_size,
                              hipStream_t stream) {
    const float* x = (const float*)d_in[0];
    float* out = (float*)d_out;
    float* im_plane = (float*)d_ws;

    const size_t total = (size_t)BATCH * S_LEN * D_LEN;
    if (ws_size < total * sizeof(float)) return;  // need 96MB scratch for imag

    fft_d_kernel<<<dim3(BATCH * S_LEN), dim3(128), 0, stream>>>(x, out, im_plane);
    fft_s_kernel<<<dim3(BATCH * D_LEN), dim3(256), 0, stream>>>(out, im_plane, out);
}

// Round 2
// 262.071 us; speedup vs baseline: 3.9720x; 3.9720x over previous
//
#include <hip/hip_runtime.h>
#include <math.h>

// out = Re(FFT2(x, axes=(1,2))), x: [B=4, S=8192, D=768] f32.
// Four-step along S (8192 = 128 x 64), then row-local FFT-768 along D.
//   B1: Y[n1][k2] = FFT64_{n2}(x[n1+128*n2])          -> row 64*n1+k2
//   B2: X[k2+64*k1] = FFT128_{n1}(W8192^{n1*k2} * Y)  -> row k2+64*k1 (in-place)
//   D : out[row] = Re(FFT768_D(row))                  (in-place per row)
// re plane = d_out, im plane = d_ws (96 MiB each).

#define BATCH 4
#define S_LEN 8192
#define D_LEN 768
#define TWO_PI 6.28318530717958647692f

// ---------------- B1: FFT-64 over n2, TD=64 cols/block ----------------
__global__ __launch_bounds__(256) void fft_s1_kernel(const float* __restrict__ x,
                                                     float* __restrict__ yre,
                                                     float* __restrict__ yim) {
    __shared__ float sre[64 * 64];
    __shared__ float sim[64 * 64];
    __shared__ float twr[32], twi[32];
    const int bid = blockIdx.x;
    const int dt = bid % 12;
    const int n1 = (bid / 12) % 128;
    const int b  = bid / (12 * 128);
    const int t = threadIdx.x;
    const int d = t & 63;
    const int d0 = dt * 64;

    if (t < 32) {
        float s, c;
        sincosf(-TWO_PI * (float)t / 64.0f, &s, &c);
        twr[t] = c; twi[t] = s;
    }

    const size_t rowbase = ((size_t)b * S_LEN + n1) * D_LEN + d0 + d;
    for (int n2 = t >> 6; n2 < 64; n2 += 4) {
        sre[n2 * 64 + d] = x[rowbase + (size_t)n2 * 128 * D_LEN];
        sim[n2 * 64 + d] = 0.0f;
    }
    __syncthreads();

    for (int sh = 5; sh >= 0; --sh) {
        const int half = 1 << sh;
        for (int i = t >> 6; i < 32; i += 4) {
            const int g = i >> sh;
            const int p = i & (half - 1);
            const int i0 = (g << (sh + 1)) + p;
            const int i1 = i0 + half;
            const int a0 = i0 * 64 + d, a1 = i1 * 64 + d;
            float ar = sre[a0], ai = sim[a0];
            float br = sre[a1], bi = sim[a1];
            sre[a0] = ar + br; sim[a0] = ai + bi;
            float dr = ar - br, di = ai - bi;
            const int q = p << (5 - sh);
            float c = twr[q], s_ = twi[q];
            sre[a1] = dr * c - di * s_;
            sim[a1] = dr * s_ + di * c;
        }
        __syncthreads();
    }

    // position j holds bin brev6(j); Y[n1][k2] -> row 64*n1 + k2
    const size_t obase = ((size_t)b * S_LEN + (size_t)n1 * 64) * D_LEN + d0 + d;
    for (int j = t >> 6; j < 64; j += 4) {
        const int k2 = (int)(__brev((unsigned)j) >> 26);
        yre[obase + (size_t)k2 * D_LEN] = sre[j * 64 + d];
        yim[obase + (size_t)k2 * D_LEN] = sim[j * 64 + d];
    }
}

// ---------------- B2: twiddle + FFT-128 over n1, TD=32, in-place ----------------
__global__ __launch_bounds__(256) void fft_s2_kernel(float* __restrict__ yre,
                                                     float* __restrict__ yim) {
    __shared__ float sre[128 * 32];
    __shared__ float sim[128 * 32];
    __shared__ float pre[128], pim[128];  // W_8192^{n1*k2}
    __shared__ float twr[64], twi[64];    // W_128^q
    const int bid = blockIdx.x;
    const int dt = bid % 24;
    const int k2 = (bid / 24) % 64;
    const int b  = bid / (24 * 64);
    const int t = threadIdx.x;
    const int d = t & 31;
    const int d0 = dt * 32;

    if (t < 128) {
        float s, c;
        sincosf(-TWO_PI * (float)(t * k2) / 8192.0f, &s, &c);
        pre[t] = c; pim[t] = s;
    } else if (t < 192) {
        const int q = t - 128;
        float s, c;
        sincosf(-TWO_PI * (float)q / 128.0f, &s, &c);
        twr[q] = c; twi[q] = s;
    }
    __syncthreads();

    const size_t base = ((size_t)b * S_LEN + k2) * D_LEN + d0 + d;
    for (int n1 = t >> 5; n1 < 128; n1 += 8) {
        float vr = yre[base + (size_t)n1 * 64 * D_LEN];
        float vi = yim[base + (size_t)n1 * 64 * D_LEN];
        float c = pre[n1], s_ = pim[n1];
        sre[n1 * 32 + d] = vr * c - vi * s_;
        sim[n1 * 32 + d] = vr * s_ + vi * c;
    }
    __syncthreads();

    for (int sh = 6; sh >= 0; --sh) {
        const int half = 1 << sh;
        for (int i = t >> 5; i < 64; i += 8) {
            const int g = i >> sh;
            const int p = i & (half - 1);
            const int i0 = (g << (sh + 1)) + p;
            const int i1 = i0 + half;
            const int a0 = i0 * 32 + d, a1 = i1 * 32 + d;
            float ar = sre[a0], ai = sim[a0];
            float br = sre[a1], bi = sim[a1];
            sre[a0] = ar + br; sim[a0] = ai + bi;
            float dr = ar - br, di = ai - bi;
            const int q = p << (6 - sh);
            float c = twr[q], s_ = twi[q];
            sre[a1] = dr * c - di * s_;
            sim[a1] = dr * s_ + di * c;
        }
        __syncthreads();
    }

    // position j holds bin k1 = brev7(j); write to row k2 + 64*k1 (owned)
    for (int j = t >> 5; j < 128; j += 8) {
        const int k1 = (int)(__brev((unsigned)j) >> 25);
        yre[base + (size_t)k1 * 64 * D_LEN] = sre[j * 32 + d];
        yim[base + (size_t)k1 * 64 * D_LEN] = sim[j * 32 + d];
    }
}

// ---------------- D: FFT-768 per row (768 = 3x256), complex in, real out ----------------
__global__ __launch_bounds__(128) void fft_d_kernel(float* __restrict__ re_io,
                                                    const float* __restrict__ im_in) {
    __shared__ float sre[768], sim[768];
    __shared__ float t256r[128], t256i[128];
    __shared__ float t768r[256], t768i[256];
    const int row = blockIdx.x;
    const int t = threadIdx.x;
    const size_t rbase = (size_t)row * D_LEN;

    {
        float s, c;
        sincosf(-TWO_PI * (float)t / 256.0f, &s, &c);
        t256r[t] = c; t256i[t] = s;
        sincosf(-TWO_PI * (float)t / 768.0f, &s, &c);
        t768r[t] = c; t768i[t] = s;
        sincosf(-TWO_PI * (float)(t + 128) / 768.0f, &s, &c);
        t768r[t + 128] = c; t768i[t + 128] = s;
    }

    for (int n = t; n < 768; n += 128) {
        const int n1 = n / 3, n2 = n - 3 * n1;
        sre[n2 * 256 + n1] = re_io[rbase + n];
        sim[n2 * 256 + n1] = im_in[rbase + n];
    }
    __syncthreads();

    for (int sh = 7; sh >= 0; --sh) {
        const int half = 1 << sh;
        for (int sub = 0; sub < 3; ++sub) {
            const int i = t;
            const int g = i >> sh, p = i & (half - 1);
            const int i0 = sub * 256 + (g << (sh + 1)) + p;
            const int i1 = i0 + half;
            float ar = sre[i0], ai = sim[i0];
            float br = sre[i1], bi = sim[i1];
            sre[i0] = ar + br; sim[i0] = ai + bi;
            float dr = ar - br, di = ai - bi;
            const int q = p << (7 - sh);
            float c = t256r[q], s_ = t256i[q];
            sre[i1] = dr * c - di * s_;
            sim[i1] = dr * s_ + di * c;
        }
        __syncthreads();
    }

    const float W3r = -0.5f, W3i = -0.86602540378443864676f;
    for (int k1 = t; k1 < 256; k1 += 128) {
        const int j = (int)(__brev((unsigned)k1) >> 24);
        float u0r = sre[j],       u0i = sim[j];
        float u1r = sre[256 + j], u1i = sim[256 + j];
        float u2r = sre[512 + j], u2i = sim[512 + j];
        float c1 = t768r[k1], s1 = t768i[k1];
        float c2 = c1 * c1 - s1 * s1, s2 = 2.0f * c1 * s1;  // W^{2k1}
        float v1r = u1r * c1 - u1i * s1, v1i = u1r * s1 + u1i * c1;
        float v2r = u2r * c2 - u2i * s2, v2i = u2r * s2 + u2i * c2;
        // k2=0: Re(u0 + v1 + v2)
        re_io[rbase + k1] = u0r + v1r + v2r;
        // k2=1: Re(u0 + v1*W3 + v2*conj(W3))
        re_io[rbase + 256 + k1] =
            u0r + (v1r * W3r - v1i * W3i) + (v2r * W3r + v2i * W3i);
        // k2=2: Re(u0 + v1*conj(W3) + v2*W3)
        re_io[rbase + 512 + k1] =
            u0r + (v1r * W3r + v1i * W3i) + (v2r * W3r - v2i * W3i);
    }
}

extern "C" void kernel_launch(void* const* d_in, const int* in_sizes, int n_in,
                              void* d_out, int out_size, void* d_ws, size_t ws_size,
                              hipStream_t stream) {
    const float* x = (const float*)d_in[0];
    float* out = (float*)d_out;
    float* im = (float*)d_ws;

    const size_t total = (size_t)BATCH * S_LEN * D_LEN;
    if (ws_size < total * sizeof(float)) return;  // need 96 MiB imag plane

    fft_s1_kernel<<<dim3(BATCH * 128 * 12), dim3(256), 0, stream>>>(x, out, im);
    fft_s2_kernel<<<dim3(BATCH * 64 * 24), dim3(256), 0, stream>>>(out, im);
    fft_d_kernel<<<dim3(BATCH * S_LEN), dim3(128), 0, stream>>>(out, im);
}

// Round 3
// 197.618 us; speedup vs baseline: 5.2675x; 1.3261x over previous
//
#include <hip/hip_runtime.h>
#include <math.h>

// out = Re(FFT2(x, axes=(1,2))), x: [B=4, S=8192, D=768] f32, x REAL.
// Hermitian: out[(S-ks)%S][(D-kd)%D] = out[ks][kd]. Compute only ks%64 <= 32.
// Four-step along S (8192 = 128 x 64), k = k2 + 64*k1, keep k2 = 0..32:
//   B1: packed-real FFT-64 over n2 (pairs of d-columns), unpack -> Y[n1][k2]
//   B2: pre-twiddle W8192^{n1*k2}, FFT-128 over n1, in place (k2 fixed)
//   D : FFT-768 along d per row, write Re to row 64*k1+k2 AND mirror row.
// Compact planes (rows rc = bb*4224 + 33*k1 + k2) for 2 batches per pass:
// 2 planes x 25.95 MB = 51.9 MB in d_ws. Two passes over batch pairs.

#define BATCH 4
#define S_LEN 8192
#define D_LEN 768
#define NK2 33
#define ROWS_PB (128 * NK2)            // 4224 compact rows per batch
#define PASS_ROWS (2 * ROWS_PB)        // 8448 rows per pass (2 batches)
#define PLANE_F ((size_t)PASS_ROWS * D_LEN)
#define TWO_PI 6.28318530717958647692f
#define LSTR 10                        // LDS row stride (floats): 8 rows + pad 2

__device__ __forceinline__ int brev6(int x) { return (int)(__brev((unsigned)x) >> 26); }
__device__ __forceinline__ int brev7(int x) { return (int)(__brev((unsigned)x) >> 25); }
__device__ __forceinline__ int brev8(int x) { return (int)(__brev((unsigned)x) >> 24); }

// ---------------- B1: packed-real FFT-64 over n2 ----------------
// Block: (bb, n1, dt). 64 d-columns = 32 packed complex columns.
__global__ __launch_bounds__(256) void fft_s1_kernel(const float* __restrict__ x,
                                                     float* __restrict__ yre,
                                                     float* __restrict__ yim,
                                                     int b0) {
    __shared__ float zre[64 * 32], zim[64 * 32];
    __shared__ float twr[32], twi[32];
    const int bid = blockIdx.x;
    const int dt = bid % 12;
    const int n1 = (bid / 12) % 128;
    const int bb = bid / (12 * 128);
    const int b = b0 + bb;
    const int t = threadIdx.x;
    const int c = t & 31;
    const int g = t >> 5;

    if (t < 32) {
        float s, co;
        sincosf(-TWO_PI * (float)t / 64.0f, &s, &co);
        twr[t] = co; twi[t] = s;
    }

    // z = x[.., 2c] + i*x[.., 2c+1]
    const size_t xbase = ((size_t)b * S_LEN + n1) * D_LEN + dt * 64 + 2 * c;
    for (int n2 = g; n2 < 64; n2 += 8) {
        const float2 v = *(const float2*)(x + xbase + (size_t)n2 * 128 * D_LEN);
        zre[n2 * 32 + c] = v.x;
        zim[n2 * 32 + c] = v.y;
    }
    __syncthreads();

    for (int sh = 5; sh >= 0; --sh) {
        const int half = 1 << sh;
        for (int i = g; i < 32; i += 8) {
            const int gg = i >> sh;
            const int p = i & (half - 1);
            const int i0 = (gg << (sh + 1)) + p;
            const int i1 = i0 + half;
            const int a0 = i0 * 32 + c, a1 = i1 * 32 + c;
            float ar = zre[a0], ai = zim[a0];
            float br = zre[a1], bi = zim[a1];
            zre[a0] = ar + br; zim[a0] = ai + bi;
            float dr = ar - br, di = ai - bi;
            const int q = p << (5 - sh);
            float co = twr[q], s = twi[q];
            zre[a1] = dr * co - di * s;
            zim[a1] = dr * s + di * co;
        }
        __syncthreads();
    }

    // Unpack: A = (Z[k]+conj(Z[-k]))/2 (even col), B = -i(Z[k]-conj(Z[-k]))/2 (odd col)
    for (int k2 = g; k2 <= 32; k2 += 8) {
        const int p1 = brev6(k2);
        const int p2 = brev6((64 - k2) & 63);
        float zr1 = zre[p1 * 32 + c], zi1 = zim[p1 * 32 + c];
        float zr2 = zre[p2 * 32 + c], zi2 = zim[p2 * 32 + c];
        float Ar = 0.5f * (zr1 + zr2), Ai = 0.5f * (zi1 - zi2);
        float Br = 0.5f * (zi1 + zi2), Bi = -0.5f * (zr1 - zr2);
        const size_t rc = (size_t)bb * ROWS_PB + (size_t)n1 * NK2 + k2;
        const size_t off = rc * D_LEN + dt * 64 + 2 * c;
        *(float2*)(yre + off) = make_float2(Ar, Br);
        *(float2*)(yim + off) = make_float2(Ai, Bi);
    }
}

// ---------------- B2: twiddle + FFT-128 over n1, in-place ----------------
__global__ __launch_bounds__(256) void fft_s2_kernel(float* __restrict__ yre,
                                                     float* __restrict__ yim) {
    __shared__ float sre[128 * 32], sim[128 * 32];
    __shared__ float prer[128], prei[128];
    __shared__ float twr[64], twi[64];
    const int bid = blockIdx.x;
    const int dt = bid % 24;
    const int k2 = (bid / 24) % NK2;
    const int bb = bid / (24 * NK2);
    const int t = threadIdx.x;
    const int d = t & 31;
    const int g = t >> 5;

    if (t < 128) {
        float s, co;
        sincosf(-TWO_PI * (float)(t * k2) / 8192.0f, &s, &co);
        prer[t] = co; prei[t] = s;
    } else if (t < 192) {
        const int q = t - 128;
        float s, co;
        sincosf(-TWO_PI * (float)q / 128.0f, &s, &co);
        twr[q] = co; twi[q] = s;
    }
    __syncthreads();

    // row j (n1 or k1) lives at rc = bb*4224 + 33*j + k2
    const size_t base = ((size_t)bb * ROWS_PB + k2) * D_LEN + dt * 32 + d;
    for (int j = g; j < 128; j += 8) {
        float vr = yre[base + (size_t)j * NK2 * D_LEN];
        float vi = yim[base + (size_t)j * NK2 * D_LEN];
        float co = prer[j], s = prei[j];
        sre[j * 32 + d] = vr * co - vi * s;
        sim[j * 32 + d] = vr * s + vi * co;
    }
    __syncthreads();

    for (int sh = 6; sh >= 0; --sh) {
        const int half = 1 << sh;
        for (int i = g; i < 64; i += 8) {
            const int gg = i >> sh;
            const int p = i & (half - 1);
            const int i0 = (gg << (sh + 1)) + p;
            const int i1 = i0 + half;
            const int a0 = i0 * 32 + d, a1 = i1 * 32 + d;
            float ar = sre[a0], ai = sim[a0];
            float br = sre[a1], bi = sim[a1];
            sre[a0] = ar + br; sim[a0] = ai + bi;
            float dr = ar - br, di = ai - bi;
            const int q = p << (6 - sh);
            float co = twr[q], s = twi[q];
            sre[a1] = dr * co - di * s;
            sim[a1] = dr * s + di * co;
        }
        __syncthreads();
    }

    for (int j = g; j < 128; j += 8) {
        const int k1 = brev7(j);
        yre[base + (size_t)k1 * NK2 * D_LEN] = sre[j * 32 + d];
        yim[base + (size_t)k1 * NK2 * D_LEN] = sim[j * 32 + d];
    }
}

// ---------------- D: FFT-768 per row, 8 rows/block, + Hermitian mirror ----------------
__global__ __launch_bounds__(256) void fft_d_kernel(const float* __restrict__ yre,
                                                    const float* __restrict__ yim,
                                                    float* __restrict__ out,
                                                    int b0) {
    __shared__ float sre[768 * LSTR], sim[768 * LSTR];  // [pos][row], pad stride 10
    __shared__ float2 t256[128];
    __shared__ float2 t768[256];
    const int t = threadIdx.x;
    const int rc0 = blockIdx.x * 8;

    if (t < 128) {
        float s, co;
        sincosf(-TWO_PI * (float)t / 256.0f, &s, &co);
        t256[t] = make_float2(co, s);
    }
    {
        float s, co;
        sincosf(-TWO_PI * (float)t / 768.0f, &s, &co);
        t768[t] = make_float2(co, s);
    }

    // Load: (r = t&7, q = t>>3); scatter pos n -> slot (n%3)*256 + n/3.
    {
        const int r = t & 7;
        const int q = t >> 3;
        const size_t grow = (size_t)(rc0 + r) * D_LEN;
        for (int j = 0; j < 12; ++j) {
            const int n = 2 * (q + 32 * j);
            const float2 vr = *(const float2*)(yre + grow + n);
            const float2 vi = *(const float2*)(yim + grow + n);
            const int La = (n % 3) * 256 + n / 3;
            sre[La * LSTR + r] = vr.x;
            sim[La * LSTR + r] = vi.x;
            const int Lb = ((n + 1) % 3) * 256 + (n + 1) / 3;
            sre[Lb * LSTR + r] = vr.y;
            sim[Lb * LSTR + r] = vi.y;
        }
    }
    __syncthreads();

    // Butterflies: thread owns row pair (2m, 2m+1) -> all LDS ops are b64.
    const int m = t & 3;
    const int q2 = t >> 2;
    float2* s2re = (float2*)sre;
    float2* s2im = (float2*)sim;   // float2 index = pos*5 + m
    for (int sh = 7; sh >= 0; --sh) {
        const int half = 1 << sh;
        #pragma unroll
        for (int jj = 0; jj < 6; ++jj) {
            const int bf = q2 + 64 * jj;          // 0..383
            const int sub = bf >> 7;
            const int i = bf & 127;
            const int gg = i >> sh;
            const int p = i & (half - 1);
            const int i0 = sub * 256 + (gg << (sh + 1)) + p;
            const int i1 = i0 + half;
            const int a0 = i0 * 5 + m, a1 = i1 * 5 + m;
            float2 ar = s2re[a0], ai = s2im[a0];
            float2 br = s2re[a1], bi = s2im[a1];
            s2re[a0] = make_float2(ar.x + br.x, ar.y + br.y);
            s2im[a0] = make_float2(ai.x + bi.x, ai.y + bi.y);
            const float2 dr = make_float2(ar.x - br.x, ar.y - br.y);
            const float2 di = make_float2(ai.x - bi.x, ai.y - bi.y);
            const float2 w = t256[p << (7 - sh)];
            s2re[a1] = make_float2(dr.x * w.x - di.x * w.y, dr.y * w.x - di.y * w.y);
            s2im[a1] = make_float2(dr.x * w.y + di.x * w.x, dr.y * w.y + di.y * w.x);
        }
        __syncthreads();
    }

    // Row decode (hoisted): rows 2m and 2m+1 of this block.
    size_t obase[2], mbase[2];
    bool domir[2];
    #pragma unroll
    for (int h = 0; h < 2; ++h) {
        const int rc = rc0 + 2 * m + h;
        const int bb = rc / ROWS_PB;
        const int qq = rc - bb * ROWS_PB;
        const int K1 = qq / NK2;
        const int K2 = qq - K1 * NK2;
        const int srow = 64 * K1 + K2;
        const size_t bs = (size_t)(b0 + bb) * S_LEN;
        obase[h] = (bs + srow) * D_LEN;
        mbase[h] = (bs + (S_LEN - srow)) * D_LEN;  // srow>=1 unless K1=K2=0
        domir[h] = (K2 >= 1 && K2 <= 31);
    }

    const float W3r = -0.5f, W3i = -0.86602540378443864676f;
    #pragma unroll
    for (int jj = 0; jj < 4; ++jj) {
        const int kk = q2 + 64 * jj;              // 0..255
        const int j8 = brev8(kk);
        const float2 u0r = s2re[j8 * 5 + m],         u0i = s2im[j8 * 5 + m];
        const float2 u1r = s2re[(256 + j8) * 5 + m], u1i = s2im[(256 + j8) * 5 + m];
        const float2 u2r = s2re[(512 + j8) * 5 + m], u2i = s2im[(512 + j8) * 5 + m];
        const float2 w = t768[kk];
        const float c1 = w.x, s1 = w.y;
        const float c2 = c1 * c1 - s1 * s1, s2_ = 2.0f * c1 * s1;
        // v = u * W, componentwise over row pair
        const float2 v1r = make_float2(u1r.x * c1 - u1i.x * s1, u1r.y * c1 - u1i.y * s1);
        const float2 v1i = make_float2(u1r.x * s1 + u1i.x * c1, u1r.y * s1 + u1i.y * c1);
        const float2 v2r = make_float2(u2r.x * c2 - u2i.x * s2_, u2r.y * c2 - u2i.y * s2_);
        const float2 v2i = make_float2(u2r.x * s2_ + u2i.x * c2, u2r.y * s2_ + u2i.y * c2);
        const float2 y0 = make_float2(u0r.x + v1r.x + v2r.x, u0r.y + v1r.y + v2r.y);
        const float2 y1 = make_float2(
            u0r.x + (v1r.x * W3r - v1i.x * W3i) + (v2r.x * W3r + v2i.x * W3i),
            u0r.y + (v1r.y * W3r - v1i.y * W3i) + (v2r.y * W3r + v2i.y * W3i));
        const float2 y2 = make_float2(
            u0r.x + (v1r.x * W3r + v1i.x * W3i) + (v2r.x * W3r - v2i.x * W3i),
            u0r.y + (v1r.y * W3r + v1i.y * W3i) + (v2r.y * W3r - v2i.y * W3i));
        const int d0 = kk, d1 = 256 + kk, d2 = 512 + kk;
        const int md0 = (kk == 0) ? 0 : (768 - kk);
        const int md1 = 512 - kk, md2 = 256 - kk;
        const float yv[2][3] = {{y0.x, y1.x, y2.x}, {y0.y, y1.y, y2.y}};
        #pragma unroll
        for (int h = 0; h < 2; ++h) {
            out[obase[h] + d0] = yv[h][0];
            out[obase[h] + d1] = yv[h][1];
            out[obase[h] + d2] = yv[h][2];
            if (domir[h]) {
                out[mbase[h] + md0] = yv[h][0];
                out[mbase[h] + md1] = yv[h][1];
                out[mbase[h] + md2] = yv[h][2];
            }
        }
    }
}

extern "C" void kernel_launch(void* const* d_in, const int* in_sizes, int n_in,
                              void* d_out, int out_size, void* d_ws, size_t ws_size,
                              hipStream_t stream) {
    const float* x = (const float*)d_in[0];
    float* out = (float*)d_out;
    float* yre = (float*)d_ws;
    float* yim = yre + PLANE_F;

    if (ws_size < 2 * PLANE_F * sizeof(float)) return;  // 51.9 MiB needed

    for (int pass = 0; pass < 2; ++pass) {
        const int b0 = 2 * pass;
        fft_s1_kernel<<<dim3(2 * 128 * 12), dim3(256), 0, stream>>>(x, yre, yim, b0);
        fft_s2_kernel<<<dim3(2 * NK2 * 24), dim3(256), 0, stream>>>(yre, yim);
        fft_d_kernel<<<dim3(PASS_ROWS / 8), dim3(256), 0, stream>>>(yre, yim, out, b0);
    }
}

// Round 4
// 135.947 us; speedup vs baseline: 7.6570x; 1.4536x over previous
//
#include <hip/hip_runtime.h>
#include <math.h>

// out = Re(FFT2(x, axes=(1,2))), x: [B=4, S=8192, D=768] f32, x REAL.
// Hermitian: out[(S-ks)%S][(D-kd)%D] = out[ks][kd]. Compute only ks%64 <= 32.
// Four-step along S (8192 = 128 x 64), k = k2 + 64*k1, keep k2 = 0..32:
//   s1: packed-real radix-4 FFT-64 over n2, unpack -> Y[n1][k2]   (float2 plane)
//   s2: pre-twiddle W8192^{n1*k2}, radix-4+2 FFT-128 over n1, in place
//   d : radix-4 FFT-768 (3x256) along d, Re -> direct row + mirror row, coalesced
// Compact plane rows: rc = bb*4224 + n1*33 + k2. Single pass (4 batches,
// 103.8MB) if ws allows, else two passes of 2 batches (51.9MB).

#define S_LEN 8192
#define D_LEN 768
#define NK2 33
#define ROWS_PB (128 * NK2)            // 4224 rows per batch
#define TWO_PI 6.28318530717958647692f
#define LSTR 10                        // d-kernel LDS row stride (floats)

__device__ __forceinline__ int dr64(int p) {   // base-4 digit reverse, 3 digits
    return ((p & 3) << 4) | (((p >> 2) & 3) << 2) | (p >> 4);
}
__device__ __forceinline__ int dr128(int p) {  // stages [4,4,4,2]
    return ((p & 1) << 6) | (((p >> 1) & 3) << 4) | (((p >> 3) & 3) << 2) | (p >> 5);
}
__device__ __forceinline__ int dr256(int p) {  // base-4 digit reverse, 4 digits
    return ((p & 3) << 6) | (((p >> 2) & 3) << 4) | (((p >> 4) & 3) << 2) | (p >> 6);
}

// radix-4 DIF butterfly on separate re/im LDS planes, b32 [pos*32 + col] layout
#define BFLY4(zre, zim, a0, a1, a2, a3, w1, w2, w3)                            \
    {                                                                          \
        float ar = zre[a0], ai = zim[a0], br = zre[a1], bi = zim[a1];          \
        float cr = zre[a2], ci = zim[a2], er = zre[a3], ei = zim[a3];          \
        float t0r = ar + cr, t0i = ai + ci, t1r = ar - cr, t1i = ai - ci;      \
        float t2r = br + er, t2i = bi + ei, t3r = br - er, t3i = bi - ei;      \
        zre[a0] = t0r + t2r; zim[a0] = t0i + t2i;                              \
        float B1r = t1r + t3i, B1i = t1i - t3r;                                \
        zre[a1] = B1r * w1.x - B1i * w1.y; zim[a1] = B1r * w1.y + B1i * w1.x;  \
        float B2r = t0r - t2r, B2i = t0i - t2i;                                \
        zre[a2] = B2r * w2.x - B2i * w2.y; zim[a2] = B2r * w2.y + B2i * w2.x;  \
        float B3r = t1r - t3i, B3i = t1i + t3r;                                \
        zre[a3] = B3r * w3.x - B3i * w3.y; zim[a3] = B3r * w3.y + B3i * w3.x;  \
    }

// ---------------- s1: packed-real radix-4 FFT-64 over n2 ----------------
__global__ __launch_bounds__(256) void fft_s1_kernel(const float* __restrict__ x,
                                                     float2* __restrict__ Y,
                                                     int b0) {
    __shared__ float zre[64 * 32], zim[64 * 32];
    __shared__ float2 t64[64];
    const int bid = blockIdx.x;
    const int dt = bid % 12;
    const int n1 = (bid / 12) % 128;
    const int bb = bid / (12 * 128);
    const int b = b0 + bb;
    const int t = threadIdx.x;
    const int c = t & 31;
    const int g = t >> 5;

    if (t < 64) {
        float s, co;
        sincosf(-TWO_PI * (float)t / 64.0f, &s, &co);
        t64[t] = make_float2(co, s);
    }

    // z = x[.., 2c] + i*x[.., 2c+1]
    const size_t xbase = ((size_t)b * S_LEN + n1) * D_LEN + dt * 64 + 2 * c;
    for (int n2 = g; n2 < 64; n2 += 8) {
        const float2 v = *(const float2*)(x + xbase + (size_t)n2 * 128 * D_LEN);
        zre[n2 * 32 + c] = v.x;
        zim[n2 * 32 + c] = v.y;
    }
    __syncthreads();

    // stage L=64, Q=16
    #pragma unroll
    for (int it = 0; it < 2; ++it) {
        const int p = g + 8 * it;                  // 0..15
        const int a0 = p * 32 + c;
        const float2 w1 = t64[p], w2 = t64[2 * p], w3 = t64[3 * p];
        BFLY4(zre, zim, a0, a0 + 16 * 32, a0 + 32 * 32, a0 + 48 * 32, w1, w2, w3);
    }
    __syncthreads();
    // stage L=16, Q=4
    #pragma unroll
    for (int it = 0; it < 2; ++it) {
        const int i = g + 8 * it;
        const int blk = i >> 2, p = i & 3;
        const int base = blk * 16 + p;
        const int a0 = base * 32 + c;
        const float2 w1 = t64[4 * p], w2 = t64[8 * p], w3 = t64[12 * p];
        BFLY4(zre, zim, a0, a0 + 4 * 32, a0 + 8 * 32, a0 + 12 * 32, w1, w2, w3);
    }
    __syncthreads();
    // stage L=4, Q=1 (no twiddle)
    const float2 wid = make_float2(1.0f, 0.0f);
    #pragma unroll
    for (int it = 0; it < 2; ++it) {
        const int i = g + 8 * it;
        const int a0 = (4 * i) * 32 + c;
        BFLY4(zre, zim, a0, a0 + 32, a0 + 2 * 32, a0 + 3 * 32, wid, wid, wid);
    }
    __syncthreads();

    // unpack packed-real halves; position of bin k is dr64(k)
    for (int k2 = g; k2 <= 32; k2 += 8) {
        const int p1 = dr64(k2);
        const int p2 = dr64((64 - k2) & 63);
        float zr1 = zre[p1 * 32 + c], zi1 = zim[p1 * 32 + c];
        float zr2 = zre[p2 * 32 + c], zi2 = zim[p2 * 32 + c];
        float Ar = 0.5f * (zr1 + zr2), Ai = 0.5f * (zi1 - zi2);
        float Br = 0.5f * (zi1 + zi2), Bi = -0.5f * (zr1 - zr2);
        const size_t rc = (size_t)bb * ROWS_PB + (size_t)n1 * NK2 + k2;
        const size_t idx = rc * D_LEN + dt * 64 + 2 * c;   // float2 elements, even
        *(float4*)(Y + idx) = make_float4(Ar, Ai, Br, Bi);
    }
}

// ---------------- s2: pre-twiddle + radix-4+2 FFT-128 over n1 ----------------
__global__ __launch_bounds__(256) void fft_s2_kernel(float2* __restrict__ Y) {
    __shared__ float sre[128 * 32], sim[128 * 32];
    __shared__ float2 pt[128];     // W_8192^{n1*k2}
    __shared__ float2 t128[128];
    const int bid = blockIdx.x;
    const int dt = bid % 24;
    const int k2 = (bid / 24) % NK2;
    const int bb = bid / (24 * NK2);
    const int t = threadIdx.x;
    const int d = t & 31;
    const int g = t >> 5;

    if (t < 128) {
        float s, co;
        sincosf(-TWO_PI * (float)(t * k2) / 8192.0f, &s, &co);
        pt[t] = make_float2(co, s);
        sincosf(-TWO_PI * (float)t / 128.0f, &s, &co);
        t128[t] = make_float2(co, s);
    }
    __syncthreads();

    const size_t base_rc = (size_t)bb * ROWS_PB + k2;
    const int col = dt * 32 + d;
    for (int j = g; j < 128; j += 8) {
        const float2 v = Y[(base_rc + (size_t)j * NK2) * D_LEN + col];
        const float2 w = pt[j];
        sre[j * 32 + d] = v.x * w.x - v.y * w.y;
        sim[j * 32 + d] = v.x * w.y + v.y * w.x;
    }
    __syncthreads();

    // stage L=128, Q=32
    #pragma unroll
    for (int it = 0; it < 4; ++it) {
        const int p = g + 8 * it;                  // 0..31
        const int a0 = p * 32 + d;
        const float2 w1 = t128[p], w2 = t128[2 * p], w3 = t128[3 * p];
        BFLY4(sre, sim, a0, a0 + 32 * 32, a0 + 64 * 32, a0 + 96 * 32, w1, w2, w3);
    }
    __syncthreads();
    // stage L=32, Q=8
    #pragma unroll
    for (int it = 0; it < 4; ++it) {
        const int i = g + 8 * it;
        const int blk = i >> 3, p = i & 7;
        const int a0 = (blk * 32 + p) * 32 + d;
        const float2 w1 = t128[4 * p], w2 = t128[8 * p], w3 = t128[12 * p];
        BFLY4(sre, sim, a0, a0 + 8 * 32, a0 + 16 * 32, a0 + 24 * 32, w1, w2, w3);
    }
    __syncthreads();
    // stage L=8, Q=2
    #pragma unroll
    for (int it = 0; it < 4; ++it) {
        const int i = g + 8 * it;
        const int blk = i >> 1, p = i & 1;
        const int a0 = (blk * 8 + p) * 32 + d;
        const float2 w1 = t128[16 * p], w2 = t128[32 * p], w3 = t128[48 * p];
        BFLY4(sre, sim, a0, a0 + 2 * 32, a0 + 4 * 32, a0 + 6 * 32, w1, w2, w3);
    }
    __syncthreads();
    // stage L=2 (radix-2, no twiddle)
    #pragma unroll
    for (int it = 0; it < 8; ++it) {
        const int i = g + 8 * it;                  // 0..63
        const int a0 = (2 * i) * 32 + d, a1 = a0 + 32;
        float ar = sre[a0], ai = sim[a0], br = sre[a1], bi = sim[a1];
        sre[a0] = ar + br; sim[a0] = ai + bi;
        sre[a1] = ar - br; sim[a1] = ai - bi;
    }
    __syncthreads();

    for (int j = g; j < 128; j += 8) {
        const int k1 = dr128(j);
        Y[(base_rc + (size_t)k1 * NK2) * D_LEN + col] =
            make_float2(sre[j * 32 + d], sim[j * 32 + d]);
    }
}

// ---------------- d: radix-4 FFT-768 per row + Hermitian mirror ----------------
__global__ __launch_bounds__(256) void fft_d_kernel(const float2* __restrict__ Y,
                                                    float* __restrict__ out,
                                                    int b0) {
    __shared__ float sre[768 * LSTR], sim[768 * LSTR];  // [pos][8 rows + pad2]
    __shared__ float2 t256[192];
    __shared__ float2 t768[256];
    const int t = threadIdx.x;
    const int rc0 = blockIdx.x * 8;

    if (t < 192) {
        float s, co;
        sincosf(-TWO_PI * (float)t / 256.0f, &s, &co);
        t256[t] = make_float2(co, s);
    }
    {
        float s, co;
        sincosf(-TWO_PI * (float)t / 768.0f, &s, &co);
        t768[t] = make_float2(co, s);
    }

    // load: scatter pos n -> slot (n%3)*256 + n/3
    {
        const int r = t & 7;
        const int q = t >> 3;                       // 0..31
        const size_t grow = (size_t)(rc0 + r) * D_LEN;
        #pragma unroll
        for (int jl = 0; jl < 24; ++jl) {
            const int n = q + 32 * jl;
            const float2 v = Y[grow + n];
            const int slot = (n % 3) * 256 + n / 3;
            sre[slot * LSTR + r] = v.x;
            sim[slot * LSTR + r] = v.y;
        }
    }
    __syncthreads();

    // butterflies: thread owns row pair (2m, 2m+1); float2 idx = pos*5 + m
    const int m = t & 3;
    const int q2 = t >> 2;                          // 0..63
    float2* s2re = (float2*)sre;
    float2* s2im = (float2*)sim;

#define BFLY4V(a0, a1, a2, a3, w1, w2, w3)                                      \
    {                                                                           \
        float2 ar = s2re[a0], ai = s2im[a0], br = s2re[a1], bi = s2im[a1];      \
        float2 cr = s2re[a2], ci = s2im[a2], er = s2re[a3], ei = s2im[a3];      \
        float2 t0r = make_float2(ar.x + cr.x, ar.y + cr.y);                     \
        float2 t0i = make_float2(ai.x + ci.x, ai.y + ci.y);                     \
        float2 t1r = make_float2(ar.x - cr.x, ar.y - cr.y);                     \
        float2 t1i = make_float2(ai.x - ci.x, ai.y - ci.y);                     \
        float2 t2r = make_float2(br.x + er.x, br.y + er.y);                     \
        float2 t2i = make_float2(bi.x + ei.x, bi.y + ei.y);                     \
        float2 t3r = make_float2(br.x - er.x, br.y - er.y);                     \
        float2 t3i = make_float2(bi.x - ei.x, bi.y - ei.y);                     \
        s2re[a0] = make_float2(t0r.x + t2r.x, t0r.y + t2r.y);                   \
        s2im[a0] = make_float2(t0i.x + t2i.x, t0i.y + t2i.y);                   \
        float2 B1r = make_float2(t1r.x + t3i.x, t1r.y + t3i.y);                 \
        float2 B1i = make_float2(t1i.x - t3r.x, t1i.y - t3r.y);                 \
        s2re[a1] = make_float2(B1r.x * w1.x - B1i.x * w1.y,                     \
                               B1r.y * w1.x - B1i.y * w1.y);                    \
        s2im[a1] = make_float2(B1r.x * w1.y + B1i.x * w1.x,                     \
                               B1r.y * w1.y + B1i.y * w1.x);                    \
        float2 B2r = make_float2(t0r.x - t2r.x, t0r.y - t2r.y);                 \
        float2 B2i = make_float2(t0i.x - t2i.x, t0i.y - t2i.y);                 \
        s2re[a2] = make_float2(B2r.x * w2.x - B2i.x * w2.y,                     \
                               B2r.y * w2.x - B2i.y * w2.y);                    \
        s2im[a2] = make_float2(B2r.x * w2.y + B2i.x * w2.x,                     \
                               B2r.y * w2.y + B2i.y * w2.x);                    \
        float2 B3r = make_float2(t1r.x - t3i.x, t1r.y - t3i.y);                 \
        float2 B3i = make_float2(t1i.x + t3r.x, t1i.y + t3r.y);                 \
        s2re[a3] = make_float2(B3r.x * w3.x - B3i.x * w3.y,                     \
                               B3r.y * w3.x - B3i.y * w3.y);                    \
        s2im[a3] = make_float2(B3r.x * w3.y + B3i.x * w3.x,                     \
                               B3r.y * w3.y + B3i.y * w3.x);                    \
    }

    // stage L=256, Q=64
    #pragma unroll
    for (int jj = 0; jj < 3; ++jj) {
        const int bf = q2 + 64 * jj;
        const int sub = bf >> 6;
        const int p = bf & 63;
        const int base = sub * 256 + p;
        const int a0 = base * 5 + m;
        const float2 w1 = t256[p], w2 = t256[2 * p], w3 = t256[3 * p];
        BFLY4V(a0, a0 + 64 * 5, a0 + 128 * 5, a0 + 192 * 5, w1, w2, w3);
    }
    __syncthreads();
    // stage L=64, Q=16
    #pragma unroll
    for (int jj = 0; jj < 3; ++jj) {
        const int bf = q2 + 64 * jj;
        const int sub = bf >> 6;
        const int i = bf & 63;
        const int blk = i >> 4, p = i & 15;
        const int base = sub * 256 + blk * 64 + p;
        const int a0 = base * 5 + m;
        const float2 w1 = t256[4 * p], w2 = t256[8 * p], w3 = t256[12 * p];
        BFLY4V(a0, a0 + 16 * 5, a0 + 32 * 5, a0 + 48 * 5, w1, w2, w3);
    }
    __syncthreads();
    // stage L=16, Q=4
    #pragma unroll
    for (int jj = 0; jj < 3; ++jj) {
        const int bf = q2 + 64 * jj;
        const int sub = bf >> 6;
        const int i = bf & 63;
        const int blk = i >> 2, p = i & 3;
        const int base = sub * 256 + blk * 16 + p;
        const int a0 = base * 5 + m;
        const float2 w1 = t256[16 * p], w2 = t256[32 * p], w3 = t256[48 * p];
        BFLY4V(a0, a0 + 4 * 5, a0 + 8 * 5, a0 + 12 * 5, w1, w2, w3);
    }
    __syncthreads();
    // stage L=4, Q=1 (no twiddle)
    {
        const float2 wid = make_float2(1.0f, 0.0f);
        #pragma unroll
        for (int jj = 0; jj < 3; ++jj) {
            const int bf = q2 + 64 * jj;
            const int sub = bf >> 6;
            const int i = bf & 63;
            const int a0 = (sub * 256 + 4 * i) * 5 + m;
            BFLY4V(a0, a0 + 5, a0 + 10, a0 + 15, wid, wid, wid);
        }
    }
    __syncthreads();

    // decode 8 rows of this block
    size_t obase[8], mbase[8];
    bool domir[8];
    #pragma unroll
    for (int rr = 0; rr < 8; ++rr) {
        const int rc = rc0 + rr;
        const int bb = rc / ROWS_PB;
        const int qq = rc - bb * ROWS_PB;
        const int K1 = qq / NK2;
        const int K2 = qq - K1 * NK2;
        const int srow = 64 * K1 + K2;
        const size_t bs = (size_t)(b0 + bb) * S_LEN;
        obase[rr] = (bs + srow) * D_LEN;
        mbase[rr] = (bs + (S_LEN - srow)) * D_LEN;
        domir[rr] = (K2 >= 1 && K2 <= 31);
    }

    // combine (radix-3): thread handles bin kk = t for all 4 row pairs.
    const float W3r = -0.5f, W3i = -0.86602540378443864676f;
    const int kk = t;
    const int j8 = dr256(kk);
    const float2 w = t768[kk];
    const float c1 = w.x, s1 = w.y;
    const float c2 = c1 * c1 - s1 * s1, s2_ = 2.0f * c1 * s1;
    const int md0 = (kk == 0) ? 0 : (768 - kk);
    #pragma unroll
    for (int i2 = 0; i2 < 4; ++i2) {
        const float2 u0r = s2re[j8 * 5 + i2],         u0i = s2im[j8 * 5 + i2];
        const float2 u1r = s2re[(256 + j8) * 5 + i2], u1i = s2im[(256 + j8) * 5 + i2];
        const float2 u2r = s2re[(512 + j8) * 5 + i2], u2i = s2im[(512 + j8) * 5 + i2];
        const float2 v1r = make_float2(u1r.x * c1 - u1i.x * s1, u1r.y * c1 - u1i.y * s1);
        const float2 v1i = make_float2(u1r.x * s1 + u1i.x * c1, u1r.y * s1 + u1i.y * c1);
        const float2 v2r = make_float2(u2r.x * c2 - u2i.x * s2_, u2r.y * c2 - u2i.y * s2_);
        const float2 v2i = make_float2(u2r.x * s2_ + u2i.x * c2, u2r.y * s2_ + u2i.y * c2);
        const float2 y0 = make_float2(u0r.x + v1r.x + v2r.x, u0r.y + v1r.y + v2r.y);
        const float2 y1 = make_float2(
            u0r.x + (v1r.x * W3r - v1i.x * W3i) + (v2r.x * W3r + v2i.x * W3i),
            u0r.y + (v1r.y * W3r - v1i.y * W3i) + (v2r.y * W3r + v2i.y * W3i));
        const float2 y2 = make_float2(
            u0r.x + (v1r.x * W3r + v1i.x * W3i) + (v2r.x * W3r - v2i.x * W3i),
            u0r.y + (v1r.y * W3r + v1i.y * W3i) + (v2r.y * W3r - v2i.y * W3i));
        #pragma unroll
        for (int h = 0; h < 2; ++h) {
            const int rr = 2 * i2 + h;
            const float v0 = h ? y0.y : y0.x;
            const float v1 = h ? y1.y : y1.x;
            const float v2 = h ? y2.y : y2.x;
            out[obase[rr] + kk] = v0;
            out[obase[rr] + 256 + kk] = v1;
            out[obase[rr] + 512 + kk] = v2;
            if (domir[rr]) {
                out[mbase[rr] + md0] = v0;
                out[mbase[rr] + 512 - kk] = v1;
                out[mbase[rr] + 256 - kk] = v2;
            }
        }
    }
#undef BFLY4V
}

extern "C" void kernel_launch(void* const* d_in, const int* in_sizes, int n_in,
                              void* d_out, int out_size, void* d_ws, size_t ws_size,
                              hipStream_t stream) {
    const float* x = (const float*)d_in[0];
    float* out = (float*)d_out;
    float2* Y = (float2*)d_ws;

    const size_t full_plane_bytes = (size_t)4 * ROWS_PB * D_LEN * sizeof(float2);
    const size_t half_plane_bytes = full_plane_bytes / 2;
    int nb;
    if (ws_size >= full_plane_bytes) nb = 4;        // single pass (~104 MB)
    else if (ws_size >= half_plane_bytes) nb = 2;   // two passes (~52 MB)
    else return;

    for (int b0 = 0; b0 < 4; b0 += nb) {
        fft_s1_kernel<<<dim3(nb * 128 * 12), dim3(256), 0, stream>>>(x, Y, b0);
        fft_s2_kernel<<<dim3(nb * NK2 * 24), dim3(256), 0, stream>>>(Y);
        fft_d_kernel<<<dim3(nb * ROWS_PB / 8), dim3(256), 0, stream>>>(Y, out, b0);
    }
}

// Round 5
// 126.051 us; speedup vs baseline: 8.2581x; 1.0785x over previous
//
#include <hip/hip_runtime.h>
#include <math.h>

// out = Re(FFT2(x, axes=(1,2))), x: [B=4, S=8192, D=768] f32, x REAL.
// Hermitian: out[(S-ks)%S][(D-kd)%D] = out[ks][kd]. Compute only ks%64 <= 32.
// Four-step along S (8192 = 128 x 64), k = k2 + 64*k1, keep k2 = 0..32:
//   s1: packed-real radix-4 FFT-64 over n2, unpack -> Y[n1][k2]   (float2 plane)
//   s2: pre-twiddle W8192^{n1*k2}, radix-4+2 FFT-128 over n1, in place
//   d : radix-4 FFT-768 (3x256) along d, Re -> direct row + mirror row, coalesced
// Compact plane rows: rc = bb*4224 + n1*33 + k2.
// d-kernel LDS map: F(pos,row) = 8*pos + 2*(pos>>2) + row  (8 rows + pad 2/4pos)
//   -> uniform 4 words/bank (b64 optimum) for stages AND dr256 combine reads.

#define S_LEN 8192
#define D_LEN 768
#define NK2 33
#define ROWS_PB (128 * NK2)            // 4224 rows per batch
#define TWO_PI 6.28318530717958647692f

__device__ __forceinline__ int dr64(int p) {   // base-4 digit reverse, 3 digits
    return ((p & 3) << 4) | (((p >> 2) & 3) << 2) | (p >> 4);
}
__device__ __forceinline__ int dr128(int p) {  // stages [4,4,4,2]
    return ((p & 1) << 6) | (((p >> 1) & 3) << 4) | (((p >> 3) & 3) << 2) | (p >> 5);
}
__device__ __forceinline__ int dr256(int p) {  // base-4 digit reverse, 4 digits
    return ((p & 3) << 6) | (((p >> 2) & 3) << 4) | (((p >> 4) & 3) << 2) | (p >> 6);
}
__device__ __forceinline__ int F2(int pos) {   // float2 index of row-pair 0
    return 4 * pos + (pos >> 2);
}

// radix-4 DIF butterfly on separate re/im LDS planes, b32 [pos*32 + col] layout
#define BFLY4(zre, zim, a0, a1, a2, a3, w1, w2, w3)                            \
    {                                                                          \
        float ar = zre[a0], ai = zim[a0], br = zre[a1], bi = zim[a1];          \
        float cr = zre[a2], ci = zim[a2], er = zre[a3], ei = zim[a3];          \
        float t0r = ar + cr, t0i = ai + ci, t1r = ar - cr, t1i = ai - ci;      \
        float t2r = br + er, t2i = bi + ei, t3r = br - er, t3i = bi - ei;      \
        zre[a0] = t0r + t2r; zim[a0] = t0i + t2i;                              \
        float B1r = t1r + t3i, B1i = t1i - t3r;                                \
        zre[a1] = B1r * w1.x - B1i * w1.y; zim[a1] = B1r * w1.y + B1i * w1.x;  \
        float B2r = t0r - t2r, B2i = t0i - t2i;                                \
        zre[a2] = B2r * w2.x - B2i * w2.y; zim[a2] = B2r * w2.y + B2i * w2.x;  \
        float B3r = t1r - t3i, B3i = t1i + t3r;                                \
        zre[a3] = B3r * w3.x - B3i * w3.y; zim[a3] = B3r * w3.y + B3i * w3.x;  \
    }

// ---------------- s1: packed-real radix-4 FFT-64 over n2 ----------------
__global__ __launch_bounds__(256) void fft_s1_kernel(const float* __restrict__ x,
                                                     float2* __restrict__ Y,
                                                     int b0) {
    __shared__ float zre[64 * 32], zim[64 * 32];
    __shared__ float2 t64[64];
    const int bid = blockIdx.x;
    const int dt = bid % 12;
    const int n1 = (bid / 12) % 128;
    const int bb = bid / (12 * 128);
    const int b = b0 + bb;
    const int t = threadIdx.x;
    const int c = t & 31;
    const int g = t >> 5;

    if (t < 64) {
        float s, co;
        sincosf(-TWO_PI * (float)t / 64.0f, &s, &co);
        t64[t] = make_float2(co, s);
    }

    // z = x[.., 2c] + i*x[.., 2c+1]
    const size_t xbase = ((size_t)b * S_LEN + n1) * D_LEN + dt * 64 + 2 * c;
    for (int n2 = g; n2 < 64; n2 += 8) {
        const float2 v = *(const float2*)(x + xbase + (size_t)n2 * 128 * D_LEN);
        zre[n2 * 32 + c] = v.x;
        zim[n2 * 32 + c] = v.y;
    }
    __syncthreads();

    // stage L=64, Q=16
    #pragma unroll
    for (int it = 0; it < 2; ++it) {
        const int p = g + 8 * it;                  // 0..15
        const int a0 = p * 32 + c;
        const float2 w1 = t64[p], w2 = t64[2 * p], w3 = t64[3 * p];
        BFLY4(zre, zim, a0, a0 + 16 * 32, a0 + 32 * 32, a0 + 48 * 32, w1, w2, w3);
    }
    __syncthreads();
    // stage L=16, Q=4
    #pragma unroll
    for (int it = 0; it < 2; ++it) {
        const int i = g + 8 * it;
        const int blk = i >> 2, p = i & 3;
        const int base = blk * 16 + p;
        const int a0 = base * 32 + c;
        const float2 w1 = t64[4 * p], w2 = t64[8 * p], w3 = t64[12 * p];
        BFLY4(zre, zim, a0, a0 + 4 * 32, a0 + 8 * 32, a0 + 12 * 32, w1, w2, w3);
    }
    __syncthreads();
    // stage L=4, Q=1 (no twiddle)
    const float2 wid = make_float2(1.0f, 0.0f);
    #pragma unroll
    for (int it = 0; it < 2; ++it) {
        const int i = g + 8 * it;
        const int a0 = (4 * i) * 32 + c;
        BFLY4(zre, zim, a0, a0 + 32, a0 + 2 * 32, a0 + 3 * 32, wid, wid, wid);
    }
    __syncthreads();

    // unpack packed-real halves; position of bin k is dr64(k)
    for (int k2 = g; k2 <= 32; k2 += 8) {
        const int p1 = dr64(k2);
        const int p2 = dr64((64 - k2) & 63);
        float zr1 = zre[p1 * 32 + c], zi1 = zim[p1 * 32 + c];
        float zr2 = zre[p2 * 32 + c], zi2 = zim[p2 * 32 + c];
        float Ar = 0.5f * (zr1 + zr2), Ai = 0.5f * (zi1 - zi2);
        float Br = 0.5f * (zi1 + zi2), Bi = -0.5f * (zr1 - zr2);
        const size_t rc = (size_t)bb * ROWS_PB + (size_t)n1 * NK2 + k2;
        const size_t idx = rc * D_LEN + dt * 64 + 2 * c;   // float2 elements, even
        *(float4*)(Y + idx) = make_float4(Ar, Ai, Br, Bi);
    }
}

// ---------------- s2: pre-twiddle + radix-4+2 FFT-128 over n1 ----------------
__global__ __launch_bounds__(256) void fft_s2_kernel(float2* __restrict__ Y) {
    __shared__ float sre[128 * 32], sim[128 * 32];
    __shared__ float2 pt[128];     // W_8192^{n1*k2}
    __shared__ float2 t128[128];
    const int bid = blockIdx.x;
    const int dt = bid % 24;
    const int k2 = (bid / 24) % NK2;
    const int bb = bid / (24 * NK2);
    const int t = threadIdx.x;
    const int d = t & 31;
    const int g = t >> 5;

    if (t < 128) {
        float s, co;
        sincosf(-TWO_PI * (float)(t * k2) / 8192.0f, &s, &co);
        pt[t] = make_float2(co, s);
        sincosf(-TWO_PI * (float)t / 128.0f, &s, &co);
        t128[t] = make_float2(co, s);
    }
    __syncthreads();

    const size_t base_rc = (size_t)bb * ROWS_PB + k2;
    const int col = dt * 32 + d;
    for (int j = g; j < 128; j += 8) {
        const float2 v = Y[(base_rc + (size_t)j * NK2) * D_LEN + col];
        const float2 w = pt[j];
        sre[j * 32 + d] = v.x * w.x - v.y * w.y;
        sim[j * 32 + d] = v.x * w.y + v.y * w.x;
    }
    __syncthreads();

    // stage L=128, Q=32
    #pragma unroll
    for (int it = 0; it < 4; ++it) {
        const int p = g + 8 * it;                  // 0..31
        const int a0 = p * 32 + d;
        const float2 w1 = t128[p], w2 = t128[2 * p], w3 = t128[3 * p];
        BFLY4(sre, sim, a0, a0 + 32 * 32, a0 + 64 * 32, a0 + 96 * 32, w1, w2, w3);
    }
    __syncthreads();
    // stage L=32, Q=8
    #pragma unroll
    for (int it = 0; it < 4; ++it) {
        const int i = g + 8 * it;
        const int blk = i >> 3, p = i & 7;
        const int a0 = (blk * 32 + p) * 32 + d;
        const float2 w1 = t128[4 * p], w2 = t128[8 * p], w3 = t128[12 * p];
        BFLY4(sre, sim, a0, a0 + 8 * 32, a0 + 16 * 32, a0 + 24 * 32, w1, w2, w3);
    }
    __syncthreads();
    // stage L=8, Q=2
    #pragma unroll
    for (int it = 0; it < 4; ++it) {
        const int i = g + 8 * it;
        const int blk = i >> 1, p = i & 1;
        const int a0 = (blk * 8 + p) * 32 + d;
        const float2 w1 = t128[16 * p], w2 = t128[32 * p], w3 = t128[48 * p];
        BFLY4(sre, sim, a0, a0 + 2 * 32, a0 + 4 * 32, a0 + 6 * 32, w1, w2, w3);
    }
    __syncthreads();
    // stage L=2 (radix-2, no twiddle)
    #pragma unroll
    for (int it = 0; it < 8; ++it) {
        const int i = g + 8 * it;                  // 0..63
        const int a0 = (2 * i) * 32 + d, a1 = a0 + 32;
        float ar = sre[a0], ai = sim[a0], br = sre[a1], bi = sim[a1];
        sre[a0] = ar + br; sim[a0] = ai + bi;
        sre[a1] = ar - br; sim[a1] = ai - bi;
    }
    __syncthreads();

    for (int j = g; j < 128; j += 8) {
        const int k1 = dr128(j);
        Y[(base_rc + (size_t)k1 * NK2) * D_LEN + col] =
            make_float2(sre[j * 32 + d], sim[j * 32 + d]);
    }
}

// ---------------- d: radix-4 FFT-768 per row + Hermitian mirror ----------------
// LDS: F(pos,row) = 8*pos + 2*(pos>>2) + row; row pair via float2 idx F2(pos)+m.
__global__ __launch_bounds__(256) void fft_d_kernel(const float2* __restrict__ Y,
                                                    float* __restrict__ out,
                                                    int b0) {
    __shared__ float sre[6528], sim[6528];   // 2 x 26112 B
    __shared__ float2 t768[256];             // W768^k; W256^p = t768[3p]
    const int t = threadIdx.x;
    const int rc0 = blockIdx.x * 8;

    {
        float s, co;
        sincosf(-TWO_PI * (float)t / 768.0f, &s, &co);
        t768[t] = make_float2(co, s);
    }

    // load: row rw = t>>5 (0..7), q = t&31; 256B coalesced per wave-row
    {
        const int rw = t >> 5;
        const int q = t & 31;
        const size_t grow = (size_t)(rc0 + rw) * D_LEN;
        #pragma unroll
        for (int jl = 0; jl < 24; ++jl) {
            const int n = q + 32 * jl;
            const float2 v = Y[grow + n];
            const int pos = (n % 3) * 256 + n / 3;
            const int fi = 8 * pos + 2 * (pos >> 2) + rw;
            sre[fi] = v.x;
            sim[fi] = v.y;
        }
    }
    __syncthreads();

    // butterflies: m = t&3 row pair, q2 = t>>2 in 0..63
    const int m = t & 3;
    const int q2 = t >> 2;
    float2* s2re = (float2*)sre;
    float2* s2im = (float2*)sim;

#define BFLY4V(a0, a1, a2, a3, w1, w2, w3)                                      \
    {                                                                           \
        float2 ar = s2re[a0], ai = s2im[a0], br = s2re[a1], bi = s2im[a1];      \
        float2 cr = s2re[a2], ci = s2im[a2], er = s2re[a3], ei = s2im[a3];      \
        float2 t0r = make_float2(ar.x + cr.x, ar.y + cr.y);                     \
        float2 t0i = make_float2(ai.x + ci.x, ai.y + ci.y);                     \
        float2 t1r = make_float2(ar.x - cr.x, ar.y - cr.y);                     \
        float2 t1i = make_float2(ai.x - ci.x, ai.y - ci.y);                     \
        float2 t2r = make_float2(br.x + er.x, br.y + er.y);                     \
        float2 t2i = make_float2(bi.x + ei.x, bi.y + ei.y);                     \
        float2 t3r = make_float2(br.x - er.x, br.y - er.y);                     \
        float2 t3i = make_float2(bi.x - ei.x, bi.y - ei.y);                     \
        s2re[a0] = make_float2(t0r.x + t2r.x, t0r.y + t2r.y);                   \
        s2im[a0] = make_float2(t0i.x + t2i.x, t0i.y + t2i.y);                   \
        float2 B1r = make_float2(t1r.x + t3i.x, t1r.y + t3i.y);                 \
        float2 B1i = make_float2(t1i.x - t3r.x, t1i.y - t3r.y);                 \
        s2re[a1] = make_float2(B1r.x * w1.x - B1i.x * w1.y,                     \
                               B1r.y * w1.x - B1i.y * w1.y);                    \
        s2im[a1] = make_float2(B1r.x * w1.y + B1i.x * w1.x,                     \
                               B1r.y * w1.y + B1i.y * w1.x);                    \
        float2 B2r = make_float2(t0r.x - t2r.x, t0r.y - t2r.y);                 \
        float2 B2i = make_float2(t0i.x - t2i.x, t0i.y - t2i.y);                 \
        s2re[a2] = make_float2(B2r.x * w2.x - B2i.x * w2.y,                     \
                               B2r.y * w2.x - B2i.y * w2.y);                    \
        s2im[a2] = make_float2(B2r.x * w2.y + B2i.x * w2.x,                     \
                               B2r.y * w2.y + B2i.y * w2.x);                    \
        float2 B3r = make_float2(t1r.x - t3i.x, t1r.y - t3i.y);                 \
        float2 B3i = make_float2(t1i.x + t3r.x, t1i.y + t3r.y);                 \
        s2re[a3] = make_float2(B3r.x * w3.x - B3i.x * w3.y,                     \
                               B3r.y * w3.x - B3i.y * w3.y);                    \
        s2im[a3] = make_float2(B3r.x * w3.y + B3i.x * w3.x,                     \
                               B3r.y * w3.y + B3i.y * w3.x);                    \
    }
#define CSQ(w) make_float2((w).x * (w).x - (w).y * (w).y, 2.0f * (w).x * (w).y)
#define CMU(a, b) make_float2((a).x * (b).x - (a).y * (b).y,                    \
                              (a).x * (b).y + (a).y * (b).x)

    // stage L=256, Q=64
    #pragma unroll
    for (int jj = 0; jj < 3; ++jj) {
        const int bf = q2 + 64 * jj;
        const int sub = bf >> 6;
        const int p = bf & 63;
        const int base = sub * 256 + p;
        const float2 w1 = t768[3 * p];
        const float2 w2 = CSQ(w1);
        const float2 w3 = CMU(w1, w2);
        BFLY4V(F2(base) + m, F2(base + 64) + m, F2(base + 128) + m,
               F2(base + 192) + m, w1, w2, w3);
    }
    __syncthreads();
    // stage L=64, Q=16
    #pragma unroll
    for (int jj = 0; jj < 3; ++jj) {
        const int bf = q2 + 64 * jj;
        const int sub = bf >> 6;
        const int i = bf & 63;
        const int blk = i >> 4, p = i & 15;
        const int base = sub * 256 + blk * 64 + p;
        const float2 w1 = t768[12 * p];
        const float2 w2 = CSQ(w1);
        const float2 w3 = CMU(w1, w2);
        BFLY4V(F2(base) + m, F2(base + 16) + m, F2(base + 32) + m,
               F2(base + 48) + m, w1, w2, w3);
    }
    __syncthreads();
    // stage L=16, Q=4
    #pragma unroll
    for (int jj = 0; jj < 3; ++jj) {
        const int bf = q2 + 64 * jj;
        const int sub = bf >> 6;
        const int i = bf & 63;
        const int blk = i >> 2, p = i & 3;
        const int base = sub * 256 + blk * 16 + p;
        const float2 w1 = t768[48 * p];
        const float2 w2 = CSQ(w1);
        const float2 w3 = CMU(w1, w2);
        BFLY4V(F2(base) + m, F2(base + 4) + m, F2(base + 8) + m,
               F2(base + 12) + m, w1, w2, w3);
    }
    __syncthreads();
    // stage L=4, Q=1 (no twiddle)
    {
        const float2 wid = make_float2(1.0f, 0.0f);
        #pragma unroll
        for (int jj = 0; jj < 3; ++jj) {
            const int bf = q2 + 64 * jj;
            const int sub = bf >> 6;
            const int i = bf & 63;
            const int base = sub * 256 + 4 * i;
            BFLY4V(F2(base) + m, F2(base + 1) + m, F2(base + 2) + m,
                   F2(base + 3) + m, wid, wid, wid);
        }
    }
    __syncthreads();

    // decode 8 rows of this block
    size_t obase[8], mbase[8];
    bool domir[8];
    #pragma unroll
    for (int rr = 0; rr < 8; ++rr) {
        const int rc = rc0 + rr;
        const int bb = rc / ROWS_PB;
        const int qq = rc - bb * ROWS_PB;
        const int K1 = qq / NK2;
        const int K2 = qq - K1 * NK2;
        const int srow = 64 * K1 + K2;
        const size_t bs = (size_t)(b0 + bb) * S_LEN;
        obase[rr] = (bs + srow) * D_LEN;
        mbase[rr] = (bs + (S_LEN - srow)) * D_LEN;
        domir[rr] = (K2 >= 1 && K2 <= 31);
    }

    // combine (radix-3): thread handles bin kk = t for all 4 row pairs.
    const float W3r = -0.5f, W3i = -0.86602540378443864676f;
    const int kk = t;
    const int j8 = dr256(kk);
    const int e0 = F2(j8), e1 = F2(256 + j8), e2 = F2(512 + j8);
    const float2 w = t768[kk];
    const float c1 = w.x, s1 = w.y;
    const float c2 = c1 * c1 - s1 * s1, s2_ = 2.0f * c1 * s1;
    const int md0 = (kk == 0) ? 0 : (768 - kk);
    #pragma unroll
    for (int i2 = 0; i2 < 4; ++i2) {
        const float2 u0r = s2re[e0 + i2], u0i = s2im[e0 + i2];
        const float2 u1r = s2re[e1 + i2], u1i = s2im[e1 + i2];
        const float2 u2r = s2re[e2 + i2], u2i = s2im[e2 + i2];
        const float2 v1r = make_float2(u1r.x * c1 - u1i.x * s1, u1r.y * c1 - u1i.y * s1);
        const float2 v1i = make_float2(u1r.x * s1 + u1i.x * c1, u1r.y * s1 + u1i.y * c1);
        const float2 v2r = make_float2(u2r.x * c2 - u2i.x * s2_, u2r.y * c2 - u2i.y * s2_);
        const float2 v2i = make_float2(u2r.x * s2_ + u2i.x * c2, u2r.y * s2_ + u2i.y * c2);
        const float2 y0 = make_float2(u0r.x + v1r.x + v2r.x, u0r.y + v1r.y + v2r.y);
        const float2 y1 = make_float2(
            u0r.x + (v1r.x * W3r - v1i.x * W3i) + (v2r.x * W3r + v2i.x * W3i),
            u0r.y + (v1r.y * W3r - v1i.y * W3i) + (v2r.y * W3r + v2i.y * W3i));
        const float2 y2 = make_float2(
            u0r.x + (v1r.x * W3r + v1i.x * W3i) + (v2r.x * W3r - v2i.x * W3i),
            u0r.y + (v1r.y * W3r + v1i.y * W3i) + (v2r.y * W3r - v2i.y * W3i));
        #pragma unroll
        for (int h = 0; h < 2; ++h) {
            const int rr = 2 * i2 + h;
            const float v0 = h ? y0.y : y0.x;
            const float v1 = h ? y1.y : y1.x;
            const float v2 = h ? y2.y : y2.x;
            out[obase[rr] + kk] = v0;
            out[obase[rr] + 256 + kk] = v1;
            out[obase[rr] + 512 + kk] = v2;
            if (domir[rr]) {
                out[mbase[rr] + md0] = v0;
                out[mbase[rr] + 512 - kk] = v1;
                out[mbase[rr] + 256 - kk] = v2;
            }
        }
    }
#undef BFLY4V
#undef CSQ
#undef CMU
}

extern "C" void kernel_launch(void* const* d_in, const int* in_sizes, int n_in,
                              void* d_out, int out_size, void* d_ws, size_t ws_size,
                              hipStream_t stream) {
    const float* x = (const float*)d_in[0];
    float* out = (float*)d_out;
    float2* Y = (float2*)d_ws;

    const size_t full_plane_bytes = (size_t)4 * ROWS_PB * D_LEN * sizeof(float2);
    const size_t half_plane_bytes = full_plane_bytes / 2;
    int nb;
    if (ws_size >= full_plane_bytes) nb = 4;        // single pass (~104 MB)
    else if (ws_size >= half_plane_bytes) nb = 2;   // two passes (~52 MB)
    else return;

    for (int b0 = 0; b0 < 4; b0 += nb) {
        fft_s1_kernel<<<dim3(nb * 128 * 12), dim3(256), 0, stream>>>(x, Y, b0);
        fft_s2_kernel<<<dim3(nb * NK2 * 24), dim3(256), 0, stream>>>(Y);
        fft_d_kernel<<<dim3(nb * ROWS_PB / 8), dim3(256), 0, stream>>>(Y, out, b0);
    }
}

// Round 6
// 122.776 us; speedup vs baseline: 8.4785x; 1.0267x over previous
//
#include <hip/hip_runtime.h>
#include <math.h>

// out = Re(FFT2(x, axes=(1,2))), x: [B=4, S=8192, D=768] f32, x REAL.
// Hermitian: out[(S-ks)%S][(D-kd)%D] = out[ks][kd]. Compute only ks%64 <= 32.
// Four-step along S (8192 = 128 x 64), k = k2 + 64*k1, keep k2 = 0..32:
//   s1: packed-real register FFT-64 (8x8 Cooley-Tukey) over n2 -> Y[n1][k2]
//   s2: pre-twiddle W8192^{n1*k2}, radix-4+2 FFT-128 over n1, in place
//   d : radix-4 FFT-768 (3x256) along d, Re -> direct row + mirror row, coalesced
// Compact plane rows: rc = bb*4224 + n1*33 + k2.

#define S_LEN 8192
#define D_LEN 768
#define NK2 33
#define ROWS_PB (128 * NK2)            // 4224 rows per batch
#define TWO_PI 6.28318530717958647692f

__device__ __forceinline__ int dr128(int p) {  // stages [4,4,4,2]
    return ((p & 1) << 6) | (((p >> 1) & 3) << 4) | (((p >> 3) & 3) << 2) | (p >> 5);
}
__device__ __forceinline__ int dr256(int p) {  // base-4 digit reverse, 4 digits
    return ((p & 3) << 6) | (((p >> 2) & 3) << 4) | (((p >> 4) & 3) << 2) | (p >> 6);
}
__device__ __forceinline__ int F2(int pos) {   // d-kernel float2 index of row-pair 0
    return 4 * pos + (pos >> 2);
}

__device__ __forceinline__ float2 cadd(float2 a, float2 b) {
    return make_float2(a.x + b.x, a.y + b.y);
}
__device__ __forceinline__ float2 csub(float2 a, float2 b) {
    return make_float2(a.x - b.x, a.y - b.y);
}
__device__ __forceinline__ float2 cmulf(float2 a, float2 b) {
    return make_float2(a.x * b.x - a.y * b.y, a.x * b.y + a.y * b.x);
}
__device__ __forceinline__ float2 mul_mi(float2 a) {   // a * (-i)
    return make_float2(a.y, -a.x);
}

// 8-point DIF FFT, natural-in natural-out, constant twiddles, all registers.
__device__ __forceinline__ void fft8(const float2* a, float2* X) {
    const float R2 = 0.70710678118654752440f;
    float2 u0 = cadd(a[0], a[4]), v0 = csub(a[0], a[4]);
    float2 u1 = cadd(a[1], a[5]), v1 = csub(a[1], a[5]);
    float2 u2 = cadd(a[2], a[6]), v2 = csub(a[2], a[6]);
    float2 u3 = cadd(a[3], a[7]), v3 = csub(a[3], a[7]);
    v1 = make_float2(R2 * (v1.x + v1.y), R2 * (v1.y - v1.x));   // *W8^1
    v2 = mul_mi(v2);                                            // *W8^2
    v3 = make_float2(R2 * (v3.y - v3.x), -R2 * (v3.x + v3.y));  // *W8^3
    float2 e0 = cadd(u0, u2), o0 = csub(u0, u2);
    float2 e1 = cadd(u1, u3), o1 = mul_mi(csub(u1, u3));
    X[0] = cadd(e0, e1); X[4] = csub(e0, e1);
    X[2] = cadd(o0, o1); X[6] = csub(o0, o1);
    float2 f0 = cadd(v0, v2), p0 = csub(v0, v2);
    float2 f1 = cadd(v1, v3), p1 = mul_mi(csub(v1, v3));
    X[1] = cadd(f0, f1); X[5] = csub(f0, f1);
    X[3] = cadd(p0, p1); X[7] = csub(p0, p1);
}

// radix-4 DIF butterfly on separate re/im LDS planes, b32 [pos*32 + col] layout
#define BFLY4(zre, zim, a0, a1, a2, a3, w1, w2, w3)                            \
    {                                                                          \
        float ar = zre[a0], ai = zim[a0], br = zre[a1], bi = zim[a1];          \
        float cr = zre[a2], ci = zim[a2], er = zre[a3], ei = zim[a3];          \
        float t0r = ar + cr, t0i = ai + ci, t1r = ar - cr, t1i = ai - ci;      \
        float t2r = br + er, t2i = bi + ei, t3r = br - er, t3i = bi - ei;      \
        zre[a0] = t0r + t2r; zim[a0] = t0i + t2i;                              \
        float B1r = t1r + t3i, B1i = t1i - t3r;                                \
        zre[a1] = B1r * w1.x - B1i * w1.y; zim[a1] = B1r * w1.y + B1i * w1.x;  \
        float B2r = t0r - t2r, B2i = t0i - t2i;                                \
        zre[a2] = B2r * w2.x - B2i * w2.y; zim[a2] = B2r * w2.y + B2i * w2.x;  \
        float B3r = t1r - t3i, B3i = t1i + t3r;                                \
        zre[a3] = B3r * w3.x - B3i * w3.y; zim[a3] = B3r * w3.y + B3i * w3.x;  \
    }

// ---------------- s1: packed-real register FFT-64 (8x8) over n2 ----------------
// n2 = na + 8*nb; k = kb + 8*ka. Thread = (na, c): 8 points in registers.
__global__ __launch_bounds__(256) void fft_s1_kernel(const float* __restrict__ x,
                                                     float2* __restrict__ Y,
                                                     int b0) {
    __shared__ float2 Z[64 * 33];                  // [pos][32 cols + pad]
    const int bid = blockIdx.x;
    const int dt = bid % 12;
    const int n1 = (bid / 12) % 128;
    const int bb = bid / (12 * 128);
    const int b = b0 + bb;
    const int t = threadIdx.x;
    const int c = t & 31;
    const int na = t >> 5;                         // 0..7

    // load 8 points (rows n1 + 128*(na + 8*nb)) straight into registers
    float2 v[8];
    const size_t xbase = ((size_t)b * S_LEN + n1 + 128 * na) * D_LEN + dt * 64 + 2 * c;
    #pragma unroll
    for (int nb2 = 0; nb2 < 8; ++nb2) {
        v[nb2] = *(const float2*)(x + xbase + (size_t)nb2 * 1024 * D_LEN);
    }

    // inner FFT8 over nb -> g[kb] natural order
    float2 g[8];
    fft8(v, g);

    // twiddle: g[kb] *= W64^{na*kb} via recurrence from w = W64^{na}
    {
        float s, co;
        sincosf(-TWO_PI * (float)na / 64.0f, &s, &co);
        const float2 w = make_float2(co, s);
        float2 wk = w;
        #pragma unroll
        for (int k = 1; k < 8; ++k) {
            g[k] = cmulf(g[k], wk);
            wk = cmulf(wk, w);
        }
    }

    // transpose via LDS: pos = 8*kb + na
    #pragma unroll
    for (int k = 0; k < 8; ++k) Z[(8 * k + na) * 33 + c] = g[k];
    __syncthreads();

    // outer FFT8 over na (this thread's role: kb = na variable reused)
    float2 h[8], r[8];
    #pragma unroll
    for (int j = 0; j < 8; ++j) h[j] = Z[(8 * na + j) * 33 + c];
    fft8(h, r);                                    // r[ka] = X[na + 8*ka]
    __syncthreads();                               // all reads done before overwrite
    #pragma unroll
    for (int ka = 0; ka < 8; ++ka) Z[(na + 8 * ka) * 33 + c] = r[ka];
    __syncthreads();

    // Hermitian unpack (packed-real columns 2c, 2c+1) + store
    const size_t rcb = (size_t)bb * ROWS_PB + (size_t)n1 * NK2;
    #pragma unroll
    for (int it = 0; it < 5; ++it) {
        const int k2 = na + 8 * it;
        if (k2 <= 32) {
            const float2 z1 = Z[k2 * 33 + c];
            const float2 z2 = Z[((64 - k2) & 63) * 33 + c];
            const float Ar = 0.5f * (z1.x + z2.x), Ai = 0.5f * (z1.y - z2.y);
            const float Br = 0.5f * (z1.y + z2.y), Bi = -0.5f * (z1.x - z2.x);
            const size_t idx = (rcb + k2) * D_LEN + dt * 64 + 2 * c;
            *(float4*)(Y + idx) = make_float4(Ar, Ai, Br, Bi);
        }
    }
}

// ---------------- s2: pre-twiddle + radix-4+2 FFT-128 over n1 ----------------
__global__ __launch_bounds__(256) void fft_s2_kernel(float2* __restrict__ Y) {
    __shared__ float sre[128 * 32], sim[128 * 32];
    __shared__ float2 pt[128];     // W_8192^{n1*k2}
    __shared__ float2 t128[128];
    const int bid = blockIdx.x;
    const int dt = bid % 24;
    const int k2 = (bid / 24) % NK2;
    const int bb = bid / (24 * NK2);
    const int t = threadIdx.x;
    const int d = t & 31;
    const int g = t >> 5;

    if (t < 128) {
        float s, co;
        sincosf(-TWO_PI * (float)(t * k2) / 8192.0f, &s, &co);
        pt[t] = make_float2(co, s);
        sincosf(-TWO_PI * (float)t / 128.0f, &s, &co);
        t128[t] = make_float2(co, s);
    }
    __syncthreads();

    const size_t base_rc = (size_t)bb * ROWS_PB + k2;
    const int col = dt * 32 + d;
    for (int j = g; j < 128; j += 8) {
        const float2 v = Y[(base_rc + (size_t)j * NK2) * D_LEN + col];
        const float2 w = pt[j];
        sre[j * 32 + d] = v.x * w.x - v.y * w.y;
        sim[j * 32 + d] = v.x * w.y + v.y * w.x;
    }
    __syncthreads();

    // stage L=128, Q=32
    #pragma unroll
    for (int it = 0; it < 4; ++it) {
        const int p = g + 8 * it;                  // 0..31
        const int a0 = p * 32 + d;
        const float2 w1 = t128[p], w2 = t128[2 * p], w3 = t128[3 * p];
        BFLY4(sre, sim, a0, a0 + 32 * 32, a0 + 64 * 32, a0 + 96 * 32, w1, w2, w3);
    }
    __syncthreads();
    // stage L=32, Q=8
    #pragma unroll
    for (int it = 0; it < 4; ++it) {
        const int i = g + 8 * it;
        const int blk = i >> 3, p = i & 7;
        const int a0 = (blk * 32 + p) * 32 + d;
        const float2 w1 = t128[4 * p], w2 = t128[8 * p], w3 = t128[12 * p];
        BFLY4(sre, sim, a0, a0 + 8 * 32, a0 + 16 * 32, a0 + 24 * 32, w1, w2, w3);
    }
    __syncthreads();
    // stage L=8, Q=2
    #pragma unroll
    for (int it = 0; it < 4; ++it) {
        const int i = g + 8 * it;
        const int blk = i >> 1, p = i & 1;
        const int a0 = (blk * 8 + p) * 32 + d;
        const float2 w1 = t128[16 * p], w2 = t128[32 * p], w3 = t128[48 * p];
        BFLY4(sre, sim, a0, a0 + 2 * 32, a0 + 4 * 32, a0 + 6 * 32, w1, w2, w3);
    }
    __syncthreads();
    // stage L=2 (radix-2, no twiddle)
    #pragma unroll
    for (int it = 0; it < 8; ++it) {
        const int i = g + 8 * it;                  // 0..63
        const int a0 = (2 * i) * 32 + d, a1 = a0 + 32;
        float ar = sre[a0], ai = sim[a0], br = sre[a1], bi = sim[a1];
        sre[a0] = ar + br; sim[a0] = ai + bi;
        sre[a1] = ar - br; sim[a1] = ai - bi;
    }
    __syncthreads();

    for (int j = g; j < 128; j += 8) {
        const int k1 = dr128(j);
        Y[(base_rc + (size_t)k1 * NK2) * D_LEN + col] =
            make_float2(sre[j * 32 + d], sim[j * 32 + d]);
    }
}

// ---------------- d: radix-4 FFT-768 per row + Hermitian mirror ----------------
// LDS: F(pos,row) = 8*pos + 2*(pos>>2) + row; row pair via float2 idx F2(pos)+m.
__global__ __launch_bounds__(256) void fft_d_kernel(const float2* __restrict__ Y,
                                                    float* __restrict__ out,
                                                    int b0) {
    __shared__ float sre[6528], sim[6528];   // 2 x 26112 B
    __shared__ float2 t768[256];             // W768^k; W256^p = t768[3p]
    const int t = threadIdx.x;
    const int rc0 = blockIdx.x * 8;

    {
        float s, co;
        sincosf(-TWO_PI * (float)t / 768.0f, &s, &co);
        t768[t] = make_float2(co, s);
    }

    // load: row rw = t>>5 (0..7), q = t&31; 256B coalesced per wave-row
    {
        const int rw = t >> 5;
        const int q = t & 31;
        const size_t grow = (size_t)(rc0 + rw) * D_LEN;
        #pragma unroll
        for (int jl = 0; jl < 24; ++jl) {
            const int n = q + 32 * jl;
            const float2 v = Y[grow + n];
            const int pos = (n % 3) * 256 + n / 3;
            const int fi = 8 * pos + 2 * (pos >> 2) + rw;
            sre[fi] = v.x;
            sim[fi] = v.y;
        }
    }
    __syncthreads();

    // butterflies: m = t&3 row pair, q2 = t>>2 in 0..63
    const int m = t & 3;
    const int q2 = t >> 2;
    float2* s2re = (float2*)sre;
    float2* s2im = (float2*)sim;

#define BFLY4V(a0, a1, a2, a3, w1, w2, w3)                                      \
    {                                                                           \
        float2 ar = s2re[a0], ai = s2im[a0], br = s2re[a1], bi = s2im[a1];      \
        float2 cr = s2re[a2], ci = s2im[a2], er = s2re[a3], ei = s2im[a3];      \
        float2 t0r = make_float2(ar.x + cr.x, ar.y + cr.y);                     \
        float2 t0i = make_float2(ai.x + ci.x, ai.y + ci.y);                     \
        float2 t1r = make_float2(ar.x - cr.x, ar.y - cr.y);                     \
        float2 t1i = make_float2(ai.x - ci.x, ai.y - ci.y);                     \
        float2 t2r = make_float2(br.x + er.x, br.y + er.y);                     \
        float2 t2i = make_float2(bi.x + ei.x, bi.y + ei.y);                     \
        float2 t3r = make_float2(br.x - er.x, br.y - er.y);                     \
        float2 t3i = make_float2(bi.x - ei.x, bi.y - ei.y);                     \
        s2re[a0] = make_float2(t0r.x + t2r.x, t0r.y + t2r.y);                   \
        s2im[a0] = make_float2(t0i.x + t2i.x, t0i.y + t2i.y);                   \
        float2 B1r = make_float2(t1r.x + t3i.x, t1r.y + t3i.y);                 \
        float2 B1i = make_float2(t1i.x - t3r.x, t1i.y - t3r.y);                 \
        s2re[a1] = make_float2(B1r.x * w1.x - B1i.x * w1.y,                     \
                               B1r.y * w1.x - B1i.y * w1.y);                    \
        s2im[a1] = make_float2(B1r.x * w1.y + B1i.x * w1.x,                     \
                               B1r.y * w1.y + B1i.y * w1.x);                    \
        float2 B2r = make_float2(t0r.x - t2r.x, t0r.y - t2r.y);                 \
        float2 B2i = make_float2(t0i.x - t2i.x, t0i.y - t2i.y);                 \
        s2re[a2] = make_float2(B2r.x * w2.x - B2i.x * w2.y,                     \
                               B2r.y * w2.x - B2i.y * w2.y);                    \
        s2im[a2] = make_float2(B2r.x * w2.y + B2i.x * w2.x,                     \
                               B2r.y * w2.y + B2i.y * w2.x);                    \
        float2 B3r = make_float2(t1r.x - t3i.x, t1r.y - t3i.y);                 \
        float2 B3i = make_float2(t1i.x + t3r.x, t1i.y + t3r.y);                 \
        s2re[a3] = make_float2(B3r.x * w3.x - B3i.x * w3.y,                     \
                               B3r.y * w3.x - B3i.y * w3.y);                    \
        s2im[a3] = make_float2(B3r.x * w3.y + B3i.x * w3.x,                     \
                               B3r.y * w3.y + B3i.y * w3.x);                    \
    }
#define CSQ(w) make_float2((w).x * (w).x - (w).y * (w).y, 2.0f * (w).x * (w).y)
#define CMU(a, b) make_float2((a).x * (b).x - (a).y * (b).y,                    \
                              (a).x * (b).y + (a).y * (b).x)

    // stage L=256, Q=64
    #pragma unroll
    for (int jj = 0; jj < 3; ++jj) {
        const int bf = q2 + 64 * jj;
        const int sub = bf >> 6;
        const int p = bf & 63;
        const int base = sub * 256 + p;
        const float2 w1 = t768[3 * p];
        const float2 w2 = CSQ(w1);
        const float2 w3 = CMU(w1, w2);
        BFLY4V(F2(base) + m, F2(base + 64) + m, F2(base + 128) + m,
               F2(base + 192) + m, w1, w2, w3);
    }
    __syncthreads();
    // stage L=64, Q=16
    #pragma unroll
    for (int jj = 0; jj < 3; ++jj) {
        const int bf = q2 + 64 * jj;
        const int sub = bf >> 6;
        const int i = bf & 63;
        const int blk = i >> 4, p = i & 15;
        const int base = sub * 256 + blk * 64 + p;
        const float2 w1 = t768[12 * p];
        const float2 w2 = CSQ(w1);
        const float2 w3 = CMU(w1, w2);
        BFLY4V(F2(base) + m, F2(base + 16) + m, F2(base + 32) + m,
               F2(base + 48) + m, w1, w2, w3);
    }
    __syncthreads();
    // stage L=16, Q=4
    #pragma unroll
    for (int jj = 0; jj < 3; ++jj) {
        const int bf = q2 + 64 * jj;
        const int sub = bf >> 6;
        const int i = bf & 63;
        const int blk = i >> 2, p = i & 3;
        const int base = sub * 256 + blk * 16 + p;
        const float2 w1 = t768[48 * p];
        const float2 w2 = CSQ(w1);
        const float2 w3 = CMU(w1, w2);
        BFLY4V(F2(base) + m, F2(base + 4) + m, F2(base + 8) + m,
               F2(base + 12) + m, w1, w2, w3);
    }
    __syncthreads();
    // stage L=4, Q=1 (no twiddle)
    {
        const float2 wid = make_float2(1.0f, 0.0f);
        #pragma unroll
        for (int jj = 0; jj < 3; ++jj) {
            const int bf = q2 + 64 * jj;
            const int sub = bf >> 6;
            const int i = bf & 63;
            const int base = sub * 256 + 4 * i;
            BFLY4V(F2(base) + m, F2(base + 1) + m, F2(base + 2) + m,
                   F2(base + 3) + m, wid, wid, wid);
        }
    }
    __syncthreads();

    // decode 8 rows of this block
    size_t obase[8], mbase[8];
    bool domir[8];
    #pragma unroll
    for (int rr = 0; rr < 8; ++rr) {
        const int rc = rc0 + rr;
        const int bb = rc / ROWS_PB;
        const int qq = rc - bb * ROWS_PB;
        const int K1 = qq / NK2;
        const int K2 = qq - K1 * NK2;
        const int srow = 64 * K1 + K2;
        const size_t bs = (size_t)(b0 + bb) * S_LEN;
        obase[rr] = (bs + srow) * D_LEN;
        mbase[rr] = (bs + (S_LEN - srow)) * D_LEN;
        domir[rr] = (K2 >= 1 && K2 <= 31);
    }

    // combine (radix-3): thread handles bin kk = t for all 4 row pairs.
    const float W3r = -0.5f, W3i = -0.86602540378443864676f;
    const int kk = t;
    const int j8 = dr256(kk);
    const int e0 = F2(j8), e1 = F2(256 + j8), e2 = F2(512 + j8);
    const float2 w = t768[kk];
    const float c1 = w.x, s1 = w.y;
    const float c2 = c1 * c1 - s1 * s1, s2_ = 2.0f * c1 * s1;
    const int md0 = (kk == 0) ? 0 : (768 - kk);
    #pragma unroll
    for (int i2 = 0; i2 < 4; ++i2) {
        const float2 u0r = s2re[e0 + i2], u0i = s2im[e0 + i2];
        const float2 u1r = s2re[e1 + i2], u1i = s2im[e1 + i2];
        const float2 u2r = s2re[e2 + i2], u2i = s2im[e2 + i2];
        const float2 v1r = make_float2(u1r.x * c1 - u1i.x * s1, u1r.y * c1 - u1i.y * s1);
        const float2 v1i = make_float2(u1r.x * s1 + u1i.x * c1, u1r.y * s1 + u1i.y * c1);
        const float2 v2r = make_float2(u2r.x * c2 - u2i.x * s2_, u2r.y * c2 - u2i.y * s2_);
        const float2 v2i = make_float2(u2r.x * s2_ + u2i.x * c2, u2r.y * s2_ + u2i.y * c2);
        const float2 y0 = make_float2(u0r.x + v1r.x + v2r.x, u0r.y + v1r.y + v2r.y);
        const float2 y1 = make_float2(
            u0r.x + (v1r.x * W3r - v1i.x * W3i) + (v2r.x * W3r + v2i.x * W3i),
            u0r.y + (v1r.y * W3r - v1i.y * W3i) + (v2r.y * W3r + v2i.y * W3i));
        const float2 y2 = make_float2(
            u0r.x + (v1r.x * W3r + v1i.x * W3i) + (v2r.x * W3r - v2i.x * W3i),
            u0r.y + (v1r.y * W3r + v1i.y * W3i) + (v2r.y * W3r - v2i.y * W3i));
        #pragma unroll
        for (int h = 0; h < 2; ++h) {
            const int rr = 2 * i2 + h;
            const float v0 = h ? y0.y : y0.x;
            const float v1 = h ? y1.y : y1.x;
            const float v2 = h ? y2.y : y2.x;
            out[obase[rr] + kk] = v0;
            out[obase[rr] + 256 + kk] = v1;
            out[obase[rr] + 512 + kk] = v2;
            if (domir[rr]) {
                out[mbase[rr] + md0] = v0;
                out[mbase[rr] + 512 - kk] = v1;
                out[mbase[rr] + 256 - kk] = v2;
            }
        }
    }
#undef BFLY4V
#undef CSQ
#undef CMU
}

extern "C" void kernel_launch(void* const* d_in, const int* in_sizes, int n_in,
                              void* d_out, int out_size, void* d_ws, size_t ws_size,
                              hipStream_t stream) {
    const float* x = (const float*)d_in[0];
    float* out = (float*)d_out;
    float2* Y = (float2*)d_ws;

    const size_t full_plane_bytes = (size_t)4 * ROWS_PB * D_LEN * sizeof(float2);
    const size_t half_plane_bytes = full_plane_bytes / 2;
    int nb;
    if (ws_size >= full_plane_bytes) nb = 4;        // single pass (~104 MB)
    else if (ws_size >= half_plane_bytes) nb = 2;   // two passes (~52 MB)
    else return;

    for (int b0 = 0; b0 < 4; b0 += nb) {
        fft_s1_kernel<<<dim3(nb * 128 * 12), dim3(256), 0, stream>>>(x, Y, b0);
        fft_s2_kernel<<<dim3(nb * NK2 * 24), dim3(256), 0, stream>>>(Y);
        fft_d_kernel<<<dim3(nb * ROWS_PB / 8), dim3(256), 0, stream>>>(Y, out, b0);
    }
}

// Round 7
// 122.288 us; speedup vs baseline: 8.5123x; 1.0040x over previous
//
#include <hip/hip_runtime.h>
#include <math.h>

// out = Re(FFT2(x, axes=(1,2))), x: [B=4, S=8192, D=768] f32, x REAL.
// Hermitian: out[(S-ks)%S][(D-kd)%D] = out[ks][kd]. Compute only ks%64 <= 32.
// Four-step along S (8192 = 128 x 64), k = k2 + 64*k1, keep k2 = 0..32:
//   s1: packed-real register FFT-64 (8x8 Cooley-Tukey) over n2 -> Y[n1][k2]
//       (2 column-groups per thread: 16 loads in flight)
//   s2: pre-twiddle W8192^{n1*k2}, radix-4+2 FFT-128 over n1, in place
//   d : radix-4 FFT-768 (3x256) along d, Re -> direct row + mirror row, coalesced
// Compact plane rows: rc = bb*4224 + n1*33 + k2.

#define S_LEN 8192
#define D_LEN 768
#define NK2 33
#define ROWS_PB (128 * NK2)            // 4224 rows per batch
#define TWO_PI 6.28318530717958647692f

__device__ __forceinline__ int dr128(int p) {  // stages [4,4,4,2]
    return ((p & 1) << 6) | (((p >> 1) & 3) << 4) | (((p >> 3) & 3) << 2) | (p >> 5);
}
__device__ __forceinline__ int dr256(int p) {  // base-4 digit reverse, 4 digits
    return ((p & 3) << 6) | (((p >> 2) & 3) << 4) | (((p >> 4) & 3) << 2) | (p >> 6);
}
__device__ __forceinline__ int F2(int pos) {   // d-kernel float2 index of row-pair 0
    return 4 * pos + (pos >> 2);
}

__device__ __forceinline__ float2 cadd(float2 a, float2 b) {
    return make_float2(a.x + b.x, a.y + b.y);
}
__device__ __forceinline__ float2 csub(float2 a, float2 b) {
    return make_float2(a.x - b.x, a.y - b.y);
}
__device__ __forceinline__ float2 cmulf(float2 a, float2 b) {
    return make_float2(a.x * b.x - a.y * b.y, a.x * b.y + a.y * b.x);
}
__device__ __forceinline__ float2 mul_mi(float2 a) {   // a * (-i)
    return make_float2(a.y, -a.x);
}

// 8-point DIF FFT, natural-in natural-out, constant twiddles, all registers.
__device__ __forceinline__ void fft8(const float2* a, float2* X) {
    const float R2 = 0.70710678118654752440f;
    float2 u0 = cadd(a[0], a[4]), v0 = csub(a[0], a[4]);
    float2 u1 = cadd(a[1], a[5]), v1 = csub(a[1], a[5]);
    float2 u2 = cadd(a[2], a[6]), v2 = csub(a[2], a[6]);
    float2 u3 = cadd(a[3], a[7]), v3 = csub(a[3], a[7]);
    v1 = make_float2(R2 * (v1.x + v1.y), R2 * (v1.y - v1.x));   // *W8^1
    v2 = mul_mi(v2);                                            // *W8^2
    v3 = make_float2(R2 * (v3.y - v3.x), -R2 * (v3.x + v3.y));  // *W8^3
    float2 e0 = cadd(u0, u2), o0 = csub(u0, u2);
    float2 e1 = cadd(u1, u3), o1 = mul_mi(csub(u1, u3));
    X[0] = cadd(e0, e1); X[4] = csub(e0, e1);
    X[2] = cadd(o0, o1); X[6] = csub(o0, o1);
    float2 f0 = cadd(v0, v2), p0 = csub(v0, v2);
    float2 f1 = cadd(v1, v3), p1 = mul_mi(csub(v1, v3));
    X[1] = cadd(f0, f1); X[5] = csub(f0, f1);
    X[3] = cadd(p0, p1); X[7] = csub(p0, p1);
}

// radix-4 DIF butterfly on separate re/im LDS planes, b32 [pos*32 + col] layout
#define BFLY4(zre, zim, a0, a1, a2, a3, w1, w2, w3)                            \
    {                                                                          \
        float ar = zre[a0], ai = zim[a0], br = zre[a1], bi = zim[a1];          \
        float cr = zre[a2], ci = zim[a2], er = zre[a3], ei = zim[a3];          \
        float t0r = ar + cr, t0i = ai + ci, t1r = ar - cr, t1i = ai - ci;      \
        float t2r = br + er, t2i = bi + ei, t3r = br - er, t3i = bi - ei;      \
        zre[a0] = t0r + t2r; zim[a0] = t0i + t2i;                              \
        float B1r = t1r + t3i, B1i = t1i - t3r;                                \
        zre[a1] = B1r * w1.x - B1i * w1.y; zim[a1] = B1r * w1.y + B1i * w1.x;  \
        float B2r = t0r - t2r, B2i = t0i - t2i;                                \
        zre[a2] = B2r * w2.x - B2i * w2.y; zim[a2] = B2r * w2.y + B2i * w2.x;  \
        float B3r = t1r - t3i, B3i = t1i + t3r;                                \
        zre[a3] = B3r * w3.x - B3i * w3.y; zim[a3] = B3r * w3.y + B3i * w3.x;  \
    }

// ---------------- s1: packed-real register FFT-64 (8x8) over n2 ----------------
// n2 = na + 8*nb; k = kb + 8*ka. Thread = (na, c): 2 column-pairs, 16 pts in regs.
#define ZSTR 65
__global__ __launch_bounds__(256) void fft_s1_kernel(const float* __restrict__ x,
                                                     float2* __restrict__ Y,
                                                     int b0) {
    __shared__ float2 Z[64 * ZSTR];                // [pos][64 packed cols + pad]
    const int bid = blockIdx.x;
    const int dtt = bid % 6;                       // 128-real-col tile
    const int n1 = (bid / 6) % 128;
    const int bb = bid / (6 * 128);
    const int b = b0 + bb;
    const int t = threadIdx.x;
    const int c = t & 31;
    const int na = t >> 5;                         // 0..7

    // load 16 points (2 col groups) straight into registers: 16 loads in flight
    float2 v0[8], v1[8];
    const size_t xbase =
        ((size_t)b * S_LEN + n1 + 128 * na) * D_LEN + dtt * 128 + 2 * c;
    #pragma unroll
    for (int nb2 = 0; nb2 < 8; ++nb2) {
        const size_t off = xbase + (size_t)nb2 * 1024 * D_LEN;
        v0[nb2] = *(const float2*)(x + off);
        v1[nb2] = *(const float2*)(x + off + 64);
    }

    // inner FFT8 over nb (both groups)
    float2 g0[8], g1[8];
    fft8(v0, g0);
    fft8(v1, g1);

    // twiddle: g[kb] *= W64^{na*kb}; one recurrence shared by both groups
    {
        float s, co;
        sincosf(-TWO_PI * (float)na / 64.0f, &s, &co);
        const float2 w = make_float2(co, s);
        float2 wk = w;
        #pragma unroll
        for (int k = 1; k < 8; ++k) {
            g0[k] = cmulf(g0[k], wk);
            g1[k] = cmulf(g1[k], wk);
            wk = cmulf(wk, w);
        }
    }

    // transpose via LDS: pos = 8*kb + na
    #pragma unroll
    for (int k = 0; k < 8; ++k) {
        Z[(8 * k + na) * ZSTR + c] = g0[k];
        Z[(8 * k + na) * ZSTR + 32 + c] = g1[k];
    }
    __syncthreads();

    // outer FFT8 over na, both column groups
    float2 h[8], r0[8], r1[8];
    #pragma unroll
    for (int j = 0; j < 8; ++j) h[j] = Z[(8 * na + j) * ZSTR + c];
    fft8(h, r0);                                   // r[ka] = X[na + 8*ka]
    #pragma unroll
    for (int j = 0; j < 8; ++j) h[j] = Z[(8 * na + j) * ZSTR + 32 + c];
    fft8(h, r1);
    __syncthreads();                               // all reads done before overwrite
    #pragma unroll
    for (int ka = 0; ka < 8; ++ka) {
        Z[(na + 8 * ka) * ZSTR + c] = r0[ka];
        Z[(na + 8 * ka) * ZSTR + 32 + c] = r1[ka];
    }
    __syncthreads();

    // Hermitian unpack (packed-real col pairs) + store, both groups
    const size_t rcb = (size_t)bb * ROWS_PB + (size_t)n1 * NK2;
    #pragma unroll
    for (int it = 0; it < 5; ++it) {
        const int k2 = na + 8 * it;
        if (k2 <= 32) {
            const int pm = ((64 - k2) & 63);
            const size_t rowb = (rcb + k2) * D_LEN + dtt * 128 + 2 * c;
            {
                const float2 z1 = Z[k2 * ZSTR + c];
                const float2 z2 = Z[pm * ZSTR + c];
                const float Ar = 0.5f * (z1.x + z2.x), Ai = 0.5f * (z1.y - z2.y);
                const float Br = 0.5f * (z1.y + z2.y), Bi = -0.5f * (z1.x - z2.x);
                *(float4*)(Y + rowb) = make_float4(Ar, Ai, Br, Bi);
            }
            {
                const float2 z1 = Z[k2 * ZSTR + 32 + c];
                const float2 z2 = Z[pm * ZSTR + 32 + c];
                const float Ar = 0.5f * (z1.x + z2.x), Ai = 0.5f * (z1.y - z2.y);
                const float Br = 0.5f * (z1.y + z2.y), Bi = -0.5f * (z1.x - z2.x);
                *(float4*)(Y + rowb + 64) = make_float4(Ar, Ai, Br, Bi);
            }
        }
    }
}

// ---------------- s2: pre-twiddle + radix-4+2 FFT-128 over n1 ----------------
__global__ __launch_bounds__(256) void fft_s2_kernel(float2* __restrict__ Y) {
    __shared__ float sre[128 * 32], sim[128 * 32];
    __shared__ float2 pt[128];     // W_8192^{n1*k2}
    __shared__ float2 t128[128];
    const int bid = blockIdx.x;
    const int dt = bid % 24;
    const int k2 = (bid / 24) % NK2;
    const int bb = bid / (24 * NK2);
    const int t = threadIdx.x;
    const int d = t & 31;
    const int g = t >> 5;

    if (t < 128) {
        float s, co;
        sincosf(-TWO_PI * (float)(t * k2) / 8192.0f, &s, &co);
        pt[t] = make_float2(co, s);
        sincosf(-TWO_PI * (float)t / 128.0f, &s, &co);
        t128[t] = make_float2(co, s);
    }
    __syncthreads();

    const size_t base_rc = (size_t)bb * ROWS_PB + k2;
    const int col = dt * 32 + d;
    for (int j = g; j < 128; j += 8) {
        const float2 v = Y[(base_rc + (size_t)j * NK2) * D_LEN + col];
        const float2 w = pt[j];
        sre[j * 32 + d] = v.x * w.x - v.y * w.y;
        sim[j * 32 + d] = v.x * w.y + v.y * w.x;
    }
    __syncthreads();

    // stage L=128, Q=32
    #pragma unroll
    for (int it = 0; it < 4; ++it) {
        const int p = g + 8 * it;                  // 0..31
        const int a0 = p * 32 + d;
        const float2 w1 = t128[p], w2 = t128[2 * p], w3 = t128[3 * p];
        BFLY4(sre, sim, a0, a0 + 32 * 32, a0 + 64 * 32, a0 + 96 * 32, w1, w2, w3);
    }
    __syncthreads();
    // stage L=32, Q=8
    #pragma unroll
    for (int it = 0; it < 4; ++it) {
        const int i = g + 8 * it;
        const int blk = i >> 3, p = i & 7;
        const int a0 = (blk * 32 + p) * 32 + d;
        const float2 w1 = t128[4 * p], w2 = t128[8 * p], w3 = t128[12 * p];
        BFLY4(sre, sim, a0, a0 + 8 * 32, a0 + 16 * 32, a0 + 24 * 32, w1, w2, w3);
    }
    __syncthreads();
    // stage L=8, Q=2
    #pragma unroll
    for (int it = 0; it < 4; ++it) {
        const int i = g + 8 * it;
        const int blk = i >> 1, p = i & 1;
        const int a0 = (blk * 8 + p) * 32 + d;
        const float2 w1 = t128[16 * p], w2 = t128[32 * p], w3 = t128[48 * p];
        BFLY4(sre, sim, a0, a0 + 2 * 32, a0 + 4 * 32, a0 + 6 * 32, w1, w2, w3);
    }
    __syncthreads();
    // stage L=2 (radix-2, no twiddle)
    #pragma unroll
    for (int it = 0; it < 8; ++it) {
        const int i = g + 8 * it;                  // 0..63
        const int a0 = (2 * i) * 32 + d, a1 = a0 + 32;
        float ar = sre[a0], ai = sim[a0], br = sre[a1], bi = sim[a1];
        sre[a0] = ar + br; sim[a0] = ai + bi;
        sre[a1] = ar - br; sim[a1] = ai - bi;
    }
    __syncthreads();

    for (int j = g; j < 128; j += 8) {
        const int k1 = dr128(j);
        Y[(base_rc + (size_t)k1 * NK2) * D_LEN + col] =
            make_float2(sre[j * 32 + d], sim[j * 32 + d]);
    }
}

// ---------------- d: radix-4 FFT-768 per row + Hermitian mirror ----------------
// LDS: F(pos,row) = 8*pos + 2*(pos>>2) + row; row pair via float2 idx F2(pos)+m.
__global__ __launch_bounds__(256) void fft_d_kernel(const float2* __restrict__ Y,
                                                    float* __restrict__ out,
                                                    int b0) {
    __shared__ float sre[6528], sim[6528];   // 2 x 26112 B
    __shared__ float2 t768[256];             // W768^k; W256^p = t768[3p]
    const int t = threadIdx.x;
    const int rc0 = blockIdx.x * 8;

    {
        float s, co;
        sincosf(-TWO_PI * (float)t / 768.0f, &s, &co);
        t768[t] = make_float2(co, s);
    }

    // load: row rw = t>>5 (0..7), q = t&31; 256B coalesced per wave-row
    {
        const int rw = t >> 5;
        const int q = t & 31;
        const size_t grow = (size_t)(rc0 + rw) * D_LEN;
        #pragma unroll
        for (int jl = 0; jl < 24; ++jl) {
            const int n = q + 32 * jl;
            const float2 v = Y[grow + n];
            const int pos = (n % 3) * 256 + n / 3;
            const int fi = 8 * pos + 2 * (pos >> 2) + rw;
            sre[fi] = v.x;
            sim[fi] = v.y;
        }
    }
    __syncthreads();

    // butterflies: m = t&3 row pair, q2 = t>>2 in 0..63
    const int m = t & 3;
    const int q2 = t >> 2;
    float2* s2re = (float2*)sre;
    float2* s2im = (float2*)sim;

#define BFLY4V(a0, a1, a2, a3, w1, w2, w3)                                      \
    {                                                                           \
        float2 ar = s2re[a0], ai = s2im[a0], br = s2re[a1], bi = s2im[a1];      \
        float2 cr = s2re[a2], ci = s2im[a2], er = s2re[a3], ei = s2im[a3];      \
        float2 t0r = make_float2(ar.x + cr.x, ar.y + cr.y);                     \
        float2 t0i = make_float2(ai.x + ci.x, ai.y + ci.y);                     \
        float2 t1r = make_float2(ar.x - cr.x, ar.y - cr.y);                     \
        float2 t1i = make_float2(ai.x - ci.x, ai.y - ci.y);                     \
        float2 t2r = make_float2(br.x + er.x, br.y + er.y);                     \
        float2 t2i = make_float2(bi.x + ei.x, bi.y + ei.y);                     \
        float2 t3r = make_float2(br.x - er.x, br.y - er.y);                     \
        float2 t3i = make_float2(bi.x - ei.x, bi.y - ei.y);                     \
        s2re[a0] = make_float2(t0r.x + t2r.x, t0r.y + t2r.y);                   \
        s2im[a0] = make_float2(t0i.x + t2i.x, t0i.y + t2i.y);                   \
        float2 B1r = make_float2(t1r.x + t3i.x, t1r.y + t3i.y);                 \
        float2 B1i = make_float2(t1i.x - t3r.x, t1i.y - t3r.y);                 \
        s2re[a1] = make_float2(B1r.x * w1.x - B1i.x * w1.y,                     \
                               B1r.y * w1.x - B1i.y * w1.y);                    \
        s2im[a1] = make_float2(B1r.x * w1.y + B1i.x * w1.x,                     \
                               B1r.y * w1.y + B1i.y * w1.x);                    \
        float2 B2r = make_float2(t0r.x - t2r.x, t0r.y - t2r.y);                 \
        float2 B2i = make_float2(t0i.x - t2i.x, t0i.y - t2i.y);                 \
        s2re[a2] = make_float2(B2r.x * w2.x - B2i.x * w2.y,                     \
                               B2r.y * w2.x - B2i.y * w2.y);                    \
        s2im[a2] = make_float2(B2r.x * w2.y + B2i.x * w2.x,                     \
                               B2r.y * w2.y + B2i.y * w2.x);                    \
        float2 B3r = make_float2(t1r.x - t3i.x, t1r.y - t3i.y);                 \
        float2 B3i = make_float2(t1i.x + t3r.x, t1i.y + t3r.y);                 \
        s2re[a3] = make_float2(B3r.x * w3.x - B3i.x * w3.y,                     \
                               B3r.y * w3.x - B3i.y * w3.y);                    \
        s2im[a3] = make_float2(B3r.x * w3.y + B3i.x * w3.x,                     \
                               B3r.y * w3.y + B3i.y * w3.x);                    \
    }
#define CSQ(w) make_float2((w).x * (w).x - (w).y * (w).y, 2.0f * (w).x * (w).y)
#define CMU(a, b) make_float2((a).x * (b).x - (a).y * (b).y,                    \
                              (a).x * (b).y + (a).y * (b).x)

    // stage L=256, Q=64
    #pragma unroll
    for (int jj = 0; jj < 3; ++jj) {
        const int bf = q2 + 64 * jj;
        const int sub = bf >> 6;
        const int p = bf & 63;
        const int base = sub * 256 + p;
        const float2 w1 = t768[3 * p];
        const float2 w2 = CSQ(w1);
        const float2 w3 = CMU(w1, w2);
        BFLY4V(F2(base) + m, F2(base + 64) + m, F2(base + 128) + m,
               F2(base + 192) + m, w1, w2, w3);
    }
    __syncthreads();
    // stage L=64, Q=16
    #pragma unroll
    for (int jj = 0; jj < 3; ++jj) {
        const int bf = q2 + 64 * jj;
        const int sub = bf >> 6;
        const int i = bf & 63;
        const int blk = i >> 4, p = i & 15;
        const int base = sub * 256 + blk * 64 + p;
        const float2 w1 = t768[12 * p];
        const float2 w2 = CSQ(w1);
        const float2 w3 = CMU(w1, w2);
        BFLY4V(F2(base) + m, F2(base + 16) + m, F2(base + 32) + m,
               F2(base + 48) + m, w1, w2, w3);
    }
    __syncthreads();
    // stage L=16, Q=4
    #pragma unroll
    for (int jj = 0; jj < 3; ++jj) {
        const int bf = q2 + 64 * jj;
        const int sub = bf >> 6;
        const int i = bf & 63;
        const int blk = i >> 2, p = i & 3;
        const int base = sub * 256 + blk * 16 + p;
        const float2 w1 = t768[48 * p];
        const float2 w2 = CSQ(w1);
        const float2 w3 = CMU(w1, w2);
        BFLY4V(F2(base) + m, F2(base + 4) + m, F2(base + 8) + m,
               F2(base + 12) + m, w1, w2, w3);
    }
    __syncthreads();
    // stage L=4, Q=1 (no twiddle)
    {
        const float2 wid = make_float2(1.0f, 0.0f);
        #pragma unroll
        for (int jj = 0; jj < 3; ++jj) {
            const int bf = q2 + 64 * jj;
            const int sub = bf >> 6;
            const int i = bf & 63;
            const int base = sub * 256 + 4 * i;
            BFLY4V(F2(base) + m, F2(base + 1) + m, F2(base + 2) + m,
                   F2(base + 3) + m, wid, wid, wid);
        }
    }
    __syncthreads();

    // decode 8 rows of this block
    size_t obase[8], mbase[8];
    bool domir[8];
    #pragma unroll
    for (int rr = 0; rr < 8; ++rr) {
        const int rc = rc0 + rr;
        const int bb = rc / ROWS_PB;
        const int qq = rc - bb * ROWS_PB;
        const int K1 = qq / NK2;
        const int K2 = qq - K1 * NK2;
        const int srow = 64 * K1 + K2;
        const size_t bs = (size_t)(b0 + bb) * S_LEN;
        obase[rr] = (bs + srow) * D_LEN;
        mbase[rr] = (bs + (S_LEN - srow)) * D_LEN;
        domir[rr] = (K2 >= 1 && K2 <= 31);
    }

    // combine (radix-3): thread handles bin kk = t for all 4 row pairs.
    const float W3r = -0.5f, W3i = -0.86602540378443864676f;
    const int kk = t;
    const int j8 = dr256(kk);
    const int e0 = F2(j8), e1 = F2(256 + j8), e2 = F2(512 + j8);
    const float2 w = t768[kk];
    const float c1 = w.x, s1 = w.y;
    const float c2 = c1 * c1 - s1 * s1, s2_ = 2.0f * c1 * s1;
    const int md0 = (kk == 0) ? 0 : (768 - kk);
    #pragma unroll
    for (int i2 = 0; i2 < 4; ++i2) {
        const float2 u0r = s2re[e0 + i2], u0i = s2im[e0 + i2];
        const float2 u1r = s2re[e1 + i2], u1i = s2im[e1 + i2];
        const float2 u2r = s2re[e2 + i2], u2i = s2im[e2 + i2];
        const float2 v1r = make_float2(u1r.x * c1 - u1i.x * s1, u1r.y * c1 - u1i.y * s1);
        const float2 v1i = make_float2(u1r.x * s1 + u1i.x * c1, u1r.y * s1 + u1i.y * c1);
        const float2 v2r = make_float2(u2r.x * c2 - u2i.x * s2_, u2r.y * c2 - u2i.y * s2_);
        const float2 v2i = make_float2(u2r.x * s2_ + u2i.x * c2, u2r.y * s2_ + u2i.y * c2);
        const float2 y0 = make_float2(u0r.x + v1r.x + v2r.x, u0r.y + v1r.y + v2r.y);
        const float2 y1 = make_float2(
            u0r.x + (v1r.x * W3r - v1i.x * W3i) + (v2r.x * W3r + v2i.x * W3i),
            u0r.y + (v1r.y * W3r - v1i.y * W3i) + (v2r.y * W3r + v2i.y * W3i));
        const float2 y2 = make_float2(
            u0r.x + (v1r.x * W3r + v1i.x * W3i) + (v2r.x * W3r - v2i.x * W3i),
            u0r.y + (v1r.y * W3r + v1i.y * W3i) + (v2r.y * W3r - v2i.y * W3i));
        #pragma unroll
        for (int h = 0; h < 2; ++h) {
            const int rr = 2 * i2 + h;
            const float v0 = h ? y0.y : y0.x;
            const float v1 = h ? y1.y : y1.x;
            const float v2 = h ? y2.y : y2.x;
            out[obase[rr] + kk] = v0;
            out[obase[rr] + 256 + kk] = v1;
            out[obase[rr] + 512 + kk] = v2;
            if (domir[rr]) {
                out[mbase[rr] + md0] = v0;
                out[mbase[rr] + 512 - kk] = v1;
                out[mbase[rr] + 256 - kk] = v2;
            }
        }
    }
#undef BFLY4V
#undef CSQ
#undef CMU
}

extern "C" void kernel_launch(void* const* d_in, const int* in_sizes, int n_in,
                              void* d_out, int out_size, void* d_ws, size_t ws_size,
                              hipStream_t stream) {
    const float* x = (const float*)d_in[0];
    float* out = (float*)d_out;
    float2* Y = (float2*)d_ws;

    const size_t full_plane_bytes = (size_t)4 * ROWS_PB * D_LEN * sizeof(float2);
    const size_t half_plane_bytes = full_plane_bytes / 2;
    int nb;
    if (ws_size >= full_plane_bytes) nb = 4;        // single pass (~104 MB)
    else if (ws_size >= half_plane_bytes) nb = 2;   // two passes (~52 MB)
    else return;

    for (int b0 = 0; b0 < 4; b0 += nb) {
        fft_s1_kernel<<<dim3(nb * 128 * 6), dim3(256), 0, stream>>>(x, Y, b0);
        fft_s2_kernel<<<dim3(nb * NK2 * 24), dim3(256), 0, stream>>>(Y);
        fft_d_kernel<<<dim3(nb * ROWS_PB / 8), dim3(256), 0, stream>>>(Y, out, b0);
    }
}